// Round 4
// baseline (2087.117 us; speedup 1.0000x reference)
//
#include <hip/hip_runtime.h>

// ---------------------------------------------------------------------------
// 3-layer GraphSAGE (DGL GraphConv norm='left'), N=100k, E=1M, D=H=O=64, fp32.
// Round 4: no CSR column lists. Edges are partitioned once into 128-node
// buckets (windowed writes -> L2-resident, ~8MB instead of 133MB scatter);
// aggregation is one block per bucket accumulating gathered rows into a
// 128x64 LDS tile via LDS atomics, then one coalesced write-out.
// ---------------------------------------------------------------------------

__global__ void hist_k(const int* __restrict__ src, const int* __restrict__ dst,
                       int* __restrict__ cnt_out, int* __restrict__ cnt_in, int E) {
    int t = blockIdx.x * blockDim.x + threadIdx.x;
    if (t < E) {
        atomicAdd(&cnt_out[src[t]], 1);
        atomicAdd(&cnt_in[dst[t]], 1);
    }
}

__global__ void finalize_r_k(const int* __restrict__ cnt_out, const int* __restrict__ cnt_in,
                             float* __restrict__ r_out, float* __restrict__ r_in,
                             float* __restrict__ r_und, int N) {
    int t = blockIdx.x * blockDim.x + threadIdx.x;
    if (t < N) {
        int a = cnt_out[t], b = cnt_in[t];
        r_out[t] = 1.0f / (float)(a < 1 ? 1 : a);
        r_in[t]  = 1.0f / (float)(b < 1 ? 1 : b);
        int c = a + b;
        r_und[t] = 1.0f / (float)(c < 1 ? 1 : c);
    }
}

// per-bucket edge counts (bucket = 128 consecutive nodes)
__global__ void bucket_cnt_k(const int* __restrict__ cnt_out, const int* __restrict__ cnt_in,
                             int* __restrict__ bcnt_out, int* __restrict__ bcnt_in, int N) {
    __shared__ int s0[128], s1[128];
    int g = blockIdx.x, t = threadIdx.x;
    int node = (g << 7) + t;
    s0[t] = (node < N) ? cnt_out[node] : 0;
    s1[t] = (node < N) ? cnt_in[node] : 0;
    __syncthreads();
    for (int off = 64; off > 0; off >>= 1) {
        if (t < off) { s0[t] += s0[t + off]; s1[t] += s1[t + off]; }
        __syncthreads();
    }
    if (t == 0) { bcnt_out[g] = s0[0]; bcnt_in[g] = s1[0]; }
}

// single-block scan of bucket counts (NB <= 1023) -> bucket prefix + cursors.
// bcur arrays are padded to 16 ints (64B) per bucket to spread atomic traffic.
__global__ void bucket_scan_k(const int* __restrict__ bcnt_out, const int* __restrict__ bcnt_in,
                              int* __restrict__ bip_out, int* __restrict__ bip_in,
                              int* __restrict__ bcur_out, int* __restrict__ bcur_in, int NB) {
    __shared__ int s[1024];
    int t = threadIdx.x;
#pragma unroll 1
    for (int pass = 0; pass < 2; ++pass) {
        const int* bcnt = pass ? bcnt_in : bcnt_out;
        int* bip = pass ? bip_in : bip_out;
        int* bcur = pass ? bcur_in : bcur_out;
        int v = (t < NB) ? bcnt[t] : 0;
        s[t] = v; __syncthreads();
        for (int off = 1; off < 1024; off <<= 1) {
            int x = (t >= off) ? s[t - off] : 0;
            __syncthreads();
            s[t] += x;
            __syncthreads();
        }
        int excl = s[t] - v;
        if (t < NB) { bip[t] = excl; bcur[t << 4] = excl; }
        if (t == NB) bip[NB] = excl;   // == E
        __syncthreads();
    }
}

// scatter packed edge records into bucket-ordered arrays.
// rec = (other_node << 8) | (local_node & 127). Writes land in ~10KB windows.
__global__ void partition_k(const int* __restrict__ src, const int* __restrict__ dst,
                            int* __restrict__ bcur_out, int* __restrict__ bcur_in,
                            unsigned* __restrict__ part_out, unsigned* __restrict__ part_in, int E) {
    int e = blockIdx.x * blockDim.x + threadIdx.x;
    if (e < E) {
        int s = src[e], d = dst[e];
        int p = atomicAdd(&bcur_in[(d >> 7) << 4], 1);
        part_in[p] = ((unsigned)s << 8) | (unsigned)(d & 127);
        int q = atomicAdd(&bcur_out[(s >> 7) << 4], 1);
        part_out[q] = ((unsigned)d << 8) | (unsigned)(s & 127);
    }
}

// hs[row] = in[row] * r[row] (float4)
__global__ void scale_rows_k(const float* __restrict__ in, const float* __restrict__ r,
                             float* __restrict__ out, int n4) {
    int t = blockIdx.x * blockDim.x + threadIdx.x;
    if (t < n4) {
        float s = r[t >> 4];
        float4 v = ((const float4*)in)[t];
        v.x *= s; v.y *= s; v.z *= s; v.w *= s;
        ((float4*)out)[t] = v;
    }
}

// one block per 128-node bucket; lane = feature. Gathers hs[other] rows
// (4 in flight) and accumulates into an LDS tile with ds-atomics
// (bank = lane%32, independent of target row -> conflict-free), then one
// coalesced 32KB write-out. NDIR=2 adds both partitions (undirected layer).
template <int NDIR>
__global__ __launch_bounds__(256, 4) void agg_fused_k(
    const float* __restrict__ hs,
    const unsigned* __restrict__ partA, const int* __restrict__ bipA,
    const unsigned* __restrict__ partB, const int* __restrict__ bipB,
    float* __restrict__ agg, int N) {
    __shared__ float tile[128 * 64];
    const int g = blockIdx.x, t = threadIdx.x;
    const int lane = t & 63, wid = t >> 6;

    float4 z4 = make_float4(0.f, 0.f, 0.f, 0.f);
    for (int i = t; i < 128 * 16; i += 256) ((float4*)tile)[i] = z4;
    __syncthreads();

#pragma unroll 1
    for (int dir = 0; dir < NDIR; ++dir) {
        const unsigned* part = dir ? partB : partA;
        const int* bip = dir ? bipB : bipA;
        const int b = bip[g], e = bip[g + 1];
        for (int base = b + (wid << 6); base < e; base += 256) {
            int cnt = e - base; if (cnt > 64) cnt = 64;
            unsigned rec = (lane < cnt) ? part[base + lane] : 0u;
            int j = 0;
            for (; j + 4 <= cnt; j += 4) {
                unsigned r0 = __shfl(rec, j + 0);
                unsigned r1 = __shfl(rec, j + 1);
                unsigned r2 = __shfl(rec, j + 2);
                unsigned r3 = __shfl(rec, j + 3);
                float v0 = hs[(size_t)(r0 >> 8) * 64 + lane];
                float v1 = hs[(size_t)(r1 >> 8) * 64 + lane];
                float v2 = hs[(size_t)(r2 >> 8) * 64 + lane];
                float v3 = hs[(size_t)(r3 >> 8) * 64 + lane];
                atomicAdd(&tile[((r0 & 255u) << 6) + lane], v0);
                atomicAdd(&tile[((r1 & 255u) << 6) + lane], v1);
                atomicAdd(&tile[((r2 & 255u) << 6) + lane], v2);
                atomicAdd(&tile[((r3 & 255u) << 6) + lane], v3);
            }
            for (; j < cnt; ++j) {
                unsigned r0 = __shfl(rec, j);
                atomicAdd(&tile[((r0 & 255u) << 6) + lane],
                          hs[(size_t)(r0 >> 8) * 64 + lane]);
            }
        }
    }
    __syncthreads();

    const int node0 = g << 7;
    int nrows = N - node0; if (nrows > 128) nrows = 128;
    float4* dst4 = (float4*)(agg + (size_t)node0 * 64);
    for (int i = t; i < nrows * 16; i += 256) dst4[i] = ((float4*)tile)[i];
}

// out = [X, A] @ W + B (optional relu); optionally hs_out = out * rs[row]
// fused in the epilogue (pre-scaled features for the next layer's gather).
// 256 threads -> 64x64 tile, 4x4 per-thread. LDS 64KB. X/A tiles XOR-swizzled.
template <bool RELU, bool WRITE_HS>
__global__ __launch_bounds__(256, 2) void gemm_cat_k(
    const float* X, const float* A,
    const float* __restrict__ W, const float* __restrict__ B,
    const float* __restrict__ rs, float* __restrict__ hs_out,
    float* out, int N) {
    __shared__ float sW[128 * 64];
    __shared__ float sX[64 * 64];
    __shared__ float sA[64 * 64];
    const int tid = threadIdx.x;

    for (int i = tid; i < 2048; i += 256) ((float4*)sW)[i] = ((const float4*)W)[i];

    const int row0 = blockIdx.x * 64;
    for (int i = tid; i < 1024; i += 256) {
        int r = i >> 4, c4 = (i & 15) << 2;
        int gr = row0 + r;
        float4 xv = make_float4(0.f, 0.f, 0.f, 0.f), av = xv;
        if (gr < N) {
            xv = ((const float4*)X)[(size_t)gr * 16 + (i & 15)];
            av = ((const float4*)A)[(size_t)gr * 16 + (i & 15)];
        }
        int sc = c4 ^ ((r & 12) << 1);
        *(float4*)&sX[(r << 6) + sc] = xv;
        *(float4*)&sA[(r << 6) + sc] = av;
    }
    __syncthreads();

    const int c0 = (tid & 15) << 2;
    const int r0 = (tid >> 4) << 2;
    const int sw = (r0 & 12) << 1;

    float4 bv = *(const float4*)(B + c0);
    float acc[4][4];
#pragma unroll
    for (int i = 0; i < 4; ++i) {
        acc[i][0] = bv.x; acc[i][1] = bv.y; acc[i][2] = bv.z; acc[i][3] = bv.w;
    }

#pragma unroll 8
    for (int k = 0; k < 64; ++k) {
        const int kx = k ^ sw;
        float4 w = *(const float4*)&sW[(k << 6) + c0];
        float a0 = sX[((r0 + 0) << 6) + kx];
        float a1 = sX[((r0 + 1) << 6) + kx];
        float a2 = sX[((r0 + 2) << 6) + kx];
        float a3 = sX[((r0 + 3) << 6) + kx];
        acc[0][0] = fmaf(a0, w.x, acc[0][0]); acc[0][1] = fmaf(a0, w.y, acc[0][1]);
        acc[0][2] = fmaf(a0, w.z, acc[0][2]); acc[0][3] = fmaf(a0, w.w, acc[0][3]);
        acc[1][0] = fmaf(a1, w.x, acc[1][0]); acc[1][1] = fmaf(a1, w.y, acc[1][1]);
        acc[1][2] = fmaf(a1, w.z, acc[1][2]); acc[1][3] = fmaf(a1, w.w, acc[1][3]);
        acc[2][0] = fmaf(a2, w.x, acc[2][0]); acc[2][1] = fmaf(a2, w.y, acc[2][1]);
        acc[2][2] = fmaf(a2, w.z, acc[2][2]); acc[2][3] = fmaf(a2, w.w, acc[2][3]);
        acc[3][0] = fmaf(a3, w.x, acc[3][0]); acc[3][1] = fmaf(a3, w.y, acc[3][1]);
        acc[3][2] = fmaf(a3, w.z, acc[3][2]); acc[3][3] = fmaf(a3, w.w, acc[3][3]);
    }
#pragma unroll 8
    for (int k = 0; k < 64; ++k) {
        const int kx = k ^ sw;
        float4 w = *(const float4*)&sW[((k + 64) << 6) + c0];
        float a0 = sA[((r0 + 0) << 6) + kx];
        float a1 = sA[((r0 + 1) << 6) + kx];
        float a2 = sA[((r0 + 2) << 6) + kx];
        float a3 = sA[((r0 + 3) << 6) + kx];
        acc[0][0] = fmaf(a0, w.x, acc[0][0]); acc[0][1] = fmaf(a0, w.y, acc[0][1]);
        acc[0][2] = fmaf(a0, w.z, acc[0][2]); acc[0][3] = fmaf(a0, w.w, acc[0][3]);
        acc[1][0] = fmaf(a1, w.x, acc[1][0]); acc[1][1] = fmaf(a1, w.y, acc[1][1]);
        acc[1][2] = fmaf(a1, w.z, acc[1][2]); acc[1][3] = fmaf(a1, w.w, acc[1][3]);
        acc[2][0] = fmaf(a2, w.x, acc[2][0]); acc[2][1] = fmaf(a2, w.y, acc[2][1]);
        acc[2][2] = fmaf(a2, w.z, acc[2][2]); acc[2][3] = fmaf(a2, w.w, acc[2][3]);
        acc[3][0] = fmaf(a3, w.x, acc[3][0]); acc[3][1] = fmaf(a3, w.y, acc[3][1]);
        acc[3][2] = fmaf(a3, w.z, acc[3][2]); acc[3][3] = fmaf(a3, w.w, acc[3][3]);
    }

#pragma unroll
    for (int i = 0; i < 4; ++i) {
        int gr = row0 + r0 + i;
        if (gr < N) {
            float4 o;
            o.x = RELU ? fmaxf(acc[i][0], 0.f) : acc[i][0];
            o.y = RELU ? fmaxf(acc[i][1], 0.f) : acc[i][1];
            o.z = RELU ? fmaxf(acc[i][2], 0.f) : acc[i][2];
            o.w = RELU ? fmaxf(acc[i][3], 0.f) : acc[i][3];
            *(float4*)(out + (size_t)gr * 64 + c0) = o;
            if (WRITE_HS) {
                float rr = rs[gr];
                float4 hsv = make_float4(o.x * rr, o.y * rr, o.z * rr, o.w * rr);
                *(float4*)(hs_out + (size_t)gr * 64 + c0) = hsv;
            }
        }
    }
}

extern "C" void kernel_launch(void* const* d_in, const int* in_sizes, int n_in,
                              void* d_out, int out_size, void* d_ws, size_t ws_size,
                              hipStream_t stream) {
    const float* x  = (const float*)d_in[0];
    const int* src  = (const int*)d_in[1];
    const int* dst  = (const int*)d_in[2];
    const float* W1 = (const float*)d_in[3];
    const float* b1 = (const float*)d_in[4];
    const float* W2 = (const float*)d_in[5];
    const float* b2 = (const float*)d_in[6];
    const float* W3 = (const float*)d_in[7];
    const float* b3 = (const float*)d_in[8];

    const int N = in_sizes[0] / 64;
    const int E = in_sizes[1];
    const int NB = (N + 127) >> 7;   // 128-node buckets (NB must be <= 1023)

    // workspace layout
    float* bufH  = (float*)d_ws;                      // N*64 hidden (h1, h2)
    float* bufHS = bufH + (size_t)N * 64;             // N*64 pre-scaled features
    int* cnt_out = (int*)(bufHS + (size_t)N * 64);    // N
    int* cnt_in  = cnt_out + N;                       // N
    float* r_out = (float*)(cnt_in + N);              // N
    float* r_in  = r_out + N;                         // N
    float* r_und = r_in + N;                          // N
    int* bcnt_out = (int*)(r_und + N);                // NB
    int* bcnt_in  = bcnt_out + NB;                    // NB
    int* bip_out  = bcnt_in + NB;                     // NB+1
    int* bip_in   = bip_out + (NB + 1);               // NB+1
    int* bcur_out = bip_in + (NB + 1);                // NB*16 (64B-padded)
    int* bcur_in  = bcur_out + NB * 16;               // NB*16
    unsigned* part_out = (unsigned*)(bcur_in + NB * 16); // E
    unsigned* part_in  = part_out + E;                   // E

    float* aggB = (float*)d_out;   // aggregate buffer doubles as output

    const int TPB = 256;
    const int gE  = (E + TPB - 1) / TPB;
    const int gN  = (N + TPB - 1) / TPB;
    const int n4  = N * 16;
    const int g4  = (n4 + TPB - 1) / TPB;
    const int gGm = (N + 63) / 64;

    // --- degree/bucket build ---
    hipMemsetAsync(cnt_out, 0, 2 * (size_t)N * sizeof(int), stream);
    hist_k<<<gE, TPB, 0, stream>>>(src, dst, cnt_out, cnt_in, E);
    finalize_r_k<<<gN, TPB, 0, stream>>>(cnt_out, cnt_in, r_out, r_in, r_und, N);
    bucket_cnt_k<<<NB, 128, 0, stream>>>(cnt_out, cnt_in, bcnt_out, bcnt_in, N);
    bucket_scan_k<<<1, 1024, 0, stream>>>(bcnt_out, bcnt_in, bip_out, bip_in,
                                          bcur_out, bcur_in, NB);
    partition_k<<<gE, TPB, 0, stream>>>(src, dst, bcur_out, bcur_in,
                                        part_out, part_in, E);

    // --- layer 1: 'O' — agg over in-edges of hs0 = x * r_out ---
    scale_rows_k<<<g4, TPB, 0, stream>>>(x, r_out, bufHS, n4);
    agg_fused_k<1><<<NB, TPB, 0, stream>>>(bufHS, part_in, bip_in, nullptr, nullptr, aggB, N);
    gemm_cat_k<true, true><<<gGm, TPB, 0, stream>>>(x, aggB, W1, b1, r_in, bufHS, bufH, N);

    // --- layer 2: 'I' — agg over out-edges of hs1 = h1 * r_in ---
    agg_fused_k<1><<<NB, TPB, 0, stream>>>(bufHS, part_out, bip_out, nullptr, nullptr, aggB, N);
    gemm_cat_k<true, true><<<gGm, TPB, 0, stream>>>(bufH, aggB, W2, b2, r_und, bufHS, bufH, N);

    // --- layer 3: 'U' — agg both partitions of hs2 = h2 * r_und ---
    agg_fused_k<2><<<NB, TPB, 0, stream>>>(bufHS, part_in, bip_in, part_out, bip_out, aggB, N);
    gemm_cat_k<false, false><<<gGm, TPB, 0, stream>>>(bufH, aggB, W3, b3, nullptr, nullptr,
                                                      (float*)d_out, N);
}

// Round 5
// 535.607 us; speedup vs baseline: 3.8967x; 3.8967x over previous
//
#include <hip/hip_runtime.h>

// ---------------------------------------------------------------------------
// 3-layer GraphSAGE (DGL GraphConv norm='left'), N=100k, E=1M, D=H=O=64, fp32.
// Round 5: round-3 wave-per-node CSR gather (the fast reader) + round-4
// bucket partition (the fast writer) + per-bucket counting sort to produce
// the CSR with L2-windowed writes. fill_k's 133MB random scatter is gone.
//   hist -> bucket counts -> bucket scan -> partition (windowed) ->
//   bucket counting-sort (emits ip[] and col[]) -> per-layer {agg, gemm}.
// ---------------------------------------------------------------------------

__global__ void hist_k(const int* __restrict__ src, const int* __restrict__ dst,
                       int* __restrict__ cnt_out, int* __restrict__ cnt_in, int E) {
    int t = blockIdx.x * blockDim.x + threadIdx.x;
    if (t < E) {
        atomicAdd(&cnt_out[src[t]], 1);
        atomicAdd(&cnt_in[dst[t]], 1);
    }
}

__global__ void finalize_r_k(const int* __restrict__ cnt_out, const int* __restrict__ cnt_in,
                             float* __restrict__ r_out, float* __restrict__ r_in,
                             float* __restrict__ r_und, int N) {
    int t = blockIdx.x * blockDim.x + threadIdx.x;
    if (t < N) {
        int a = cnt_out[t], b = cnt_in[t];
        r_out[t] = 1.0f / (float)(a < 1 ? 1 : a);
        r_in[t]  = 1.0f / (float)(b < 1 ? 1 : b);
        int c = a + b;
        r_und[t] = 1.0f / (float)(c < 1 ? 1 : c);
    }
}

// per-bucket edge counts (bucket = 128 consecutive nodes)
__global__ void bucket_cnt_k(const int* __restrict__ cnt_out, const int* __restrict__ cnt_in,
                             int* __restrict__ bcnt_out, int* __restrict__ bcnt_in, int N) {
    __shared__ int s0[128], s1[128];
    int g = blockIdx.x, t = threadIdx.x;
    int node = (g << 7) + t;
    s0[t] = (node < N) ? cnt_out[node] : 0;
    s1[t] = (node < N) ? cnt_in[node] : 0;
    __syncthreads();
    for (int off = 64; off > 0; off >>= 1) {
        if (t < off) { s0[t] += s0[t + off]; s1[t] += s1[t + off]; }
        __syncthreads();
    }
    if (t == 0) { bcnt_out[g] = s0[0]; bcnt_in[g] = s1[0]; }
}

// single-block scan of bucket counts (NB <= 1024) -> bucket prefix + cursors.
// bcur arrays padded to 16 ints (64B) per bucket to spread atomic traffic.
__global__ void bucket_scan_k(const int* __restrict__ bcnt_out, const int* __restrict__ bcnt_in,
                              int* __restrict__ bip_out, int* __restrict__ bip_in,
                              int* __restrict__ bcur_out, int* __restrict__ bcur_in, int NB) {
    __shared__ int s[1024];
    int t = threadIdx.x;
#pragma unroll 1
    for (int pass = 0; pass < 2; ++pass) {
        const int* bcnt = pass ? bcnt_in : bcnt_out;
        int* bip = pass ? bip_in : bip_out;
        int* bcur = pass ? bcur_in : bcur_out;
        int v = (t < NB) ? bcnt[t] : 0;
        s[t] = v; __syncthreads();
        for (int off = 1; off < 1024; off <<= 1) {
            int x = (t >= off) ? s[t - off] : 0;
            __syncthreads();
            s[t] += x;
            __syncthreads();
        }
        int excl = s[t] - v;
        if (t < NB) { bip[t] = excl; bcur[t << 4] = excl; }
        if (t == NB) bip[NB] = excl;   // == E
        __syncthreads();
    }
}

// scatter packed edge records into bucket-ordered arrays.
// rec = (other_node << 8) | (local_node & 127). Writes land in ~5KB windows.
__global__ void partition_k(const int* __restrict__ src, const int* __restrict__ dst,
                            int* __restrict__ bcur_out, int* __restrict__ bcur_in,
                            unsigned* __restrict__ part_out, unsigned* __restrict__ part_in, int E) {
    int e = blockIdx.x * blockDim.x + threadIdx.x;
    if (e < E) {
        int s = src[e], d = dst[e];
        int p = atomicAdd(&bcur_in[(d >> 7) << 4], 1);
        part_in[p] = ((unsigned)s << 8) | (unsigned)(d & 127);
        int q = atomicAdd(&bcur_out[(s >> 7) << 4], 1);
        part_out[q] = ((unsigned)d << 8) | (unsigned)(s & 127);
    }
}

// one block per (bucket, direction): counting-sort the bucket's records by
// local node id. Emits per-node CSR pointers ip[] and the sorted col[] list.
// All record reads + col writes stay inside the bucket's L2-resident window.
__global__ void bucket_sort_k(const unsigned* __restrict__ pa, const int* __restrict__ bipa,
                              const unsigned* __restrict__ pb, const int* __restrict__ bipb,
                              int* __restrict__ ipa, int* __restrict__ ipb,
                              int* __restrict__ cola, int* __restrict__ colb, int N, int E) {
    const unsigned* part = blockIdx.y ? pb : pa;
    const int* bip = blockIdx.y ? bipb : bipa;
    int* ip  = blockIdx.y ? ipb : ipa;
    int* col = blockIdx.y ? colb : cola;
    __shared__ int cnt[128], off[128];
    const int g = blockIdx.x, t = threadIdx.x;
    if (t < 128) cnt[t] = 0;
    __syncthreads();
    const int b = bip[g], e = bip[g + 1];
    for (int i = b + t; i < e; i += 256) atomicAdd(&cnt[part[i] & 127u], 1);
    __syncthreads();
    if (t < 128) off[t] = cnt[t];
    __syncthreads();
    for (int o = 1; o < 128; o <<= 1) {
        int v = (t < 128 && t >= o) ? off[t - o] : 0;
        __syncthreads();
        if (t < 128) off[t] += v;
        __syncthreads();
    }
    // off is inclusive; exclusive base = b + off[t] - cnt[t]
    if (t < 128) {
        int base = b + off[t] - cnt[t];
        int node = (g << 7) + t;
        if (node < N) ip[node] = base;
        cnt[t] = base;               // becomes the fill cursor
    }
    if (g == 0 && t == 0) ip[N] = E;
    __syncthreads();
    for (int i = b + t; i < e; i += 256) {
        unsigned rec = part[i];
        int p = atomicAdd(&cnt[rec & 127u], 1);
        col[p] = (int)(rec >> 8);
    }
}

// hs[row] = in[row] * r[row] (float4)
__global__ void scale_rows_k(const float* __restrict__ in, const float* __restrict__ r,
                             float* __restrict__ out, int n4) {
    int t = blockIdx.x * blockDim.x + threadIdx.x;
    if (t < n4) {
        float s = r[t >> 4];
        float4 v = ((const float4*)in)[t];
        v.x *= s; v.y *= s; v.z *= s; v.w *= s;
        ((float4*)out)[t] = v;
    }
}

// one wave per node; lane = feature. agg[n][f] = sum_{nb} hs[nb][f]
// col ids loaded 64-at-a-time coalesced, broadcast via shuffle; 8 independent
// row-gathers in flight per unroll group.
__global__ void agg_k(const float* __restrict__ hs, const int* __restrict__ ip,
                      const int* __restrict__ col, float* __restrict__ agg, int N) {
    int node = (blockIdx.x * blockDim.x + threadIdx.x) >> 6;
    int lane = threadIdx.x & 63;
    if (node >= N) return;
    int b = ip[node], e = ip[node + 1];
    float acc = 0.f, acc2 = 0.f;
    for (int base = b; base < e; base += 64) {
        int cnt = e - base; if (cnt > 64) cnt = 64;
        int my = (lane < cnt) ? col[base + lane] : 0;
        int j = 0;
        for (; j + 8 <= cnt; j += 8) {
            int n0 = __shfl(my, j + 0); int n1 = __shfl(my, j + 1);
            int n2 = __shfl(my, j + 2); int n3 = __shfl(my, j + 3);
            int n4 = __shfl(my, j + 4); int n5 = __shfl(my, j + 5);
            int n6 = __shfl(my, j + 6); int n7 = __shfl(my, j + 7);
            float v0 = hs[(size_t)n0 * 64 + lane];
            float v1 = hs[(size_t)n1 * 64 + lane];
            float v2 = hs[(size_t)n2 * 64 + lane];
            float v3 = hs[(size_t)n3 * 64 + lane];
            float v4 = hs[(size_t)n4 * 64 + lane];
            float v5 = hs[(size_t)n5 * 64 + lane];
            float v6 = hs[(size_t)n6 * 64 + lane];
            float v7 = hs[(size_t)n7 * 64 + lane];
            acc += v0; acc2 += v1; acc += v2; acc2 += v3;
            acc += v4; acc2 += v5; acc += v6; acc2 += v7;
        }
        for (; j + 4 <= cnt; j += 4) {
            int n0 = __shfl(my, j + 0); int n1 = __shfl(my, j + 1);
            int n2 = __shfl(my, j + 2); int n3 = __shfl(my, j + 3);
            float v0 = hs[(size_t)n0 * 64 + lane];
            float v1 = hs[(size_t)n1 * 64 + lane];
            float v2 = hs[(size_t)n2 * 64 + lane];
            float v3 = hs[(size_t)n3 * 64 + lane];
            acc += v0; acc2 += v1; acc += v2; acc2 += v3;
        }
        for (; j < cnt; ++j) {
            int nb = __shfl(my, j);
            acc += hs[(size_t)nb * 64 + lane];
        }
    }
    agg[(size_t)node * 64 + lane] = acc + acc2;
}

__global__ void agg_dual_k(const float* __restrict__ hs,
                           const int* __restrict__ ipA, const int* __restrict__ colA,
                           const int* __restrict__ ipB, const int* __restrict__ colB,
                           float* __restrict__ agg, int N) {
    int node = (blockIdx.x * blockDim.x + threadIdx.x) >> 6;
    int lane = threadIdx.x & 63;
    if (node >= N) return;
    float acc = 0.f, acc2 = 0.f;
#pragma unroll 1
    for (int pass = 0; pass < 2; ++pass) {
        const int* ip  = pass ? ipB : ipA;
        const int* col = pass ? colB : colA;
        int b = ip[node], e = ip[node + 1];
        for (int base = b; base < e; base += 64) {
            int cnt = e - base; if (cnt > 64) cnt = 64;
            int my = (lane < cnt) ? col[base + lane] : 0;
            int j = 0;
            for (; j + 8 <= cnt; j += 8) {
                int n0 = __shfl(my, j + 0); int n1 = __shfl(my, j + 1);
                int n2 = __shfl(my, j + 2); int n3 = __shfl(my, j + 3);
                int n4 = __shfl(my, j + 4); int n5 = __shfl(my, j + 5);
                int n6 = __shfl(my, j + 6); int n7 = __shfl(my, j + 7);
                float v0 = hs[(size_t)n0 * 64 + lane];
                float v1 = hs[(size_t)n1 * 64 + lane];
                float v2 = hs[(size_t)n2 * 64 + lane];
                float v3 = hs[(size_t)n3 * 64 + lane];
                float v4 = hs[(size_t)n4 * 64 + lane];
                float v5 = hs[(size_t)n5 * 64 + lane];
                float v6 = hs[(size_t)n6 * 64 + lane];
                float v7 = hs[(size_t)n7 * 64 + lane];
                acc += v0; acc2 += v1; acc += v2; acc2 += v3;
                acc += v4; acc2 += v5; acc += v6; acc2 += v7;
            }
            for (; j + 4 <= cnt; j += 4) {
                int n0 = __shfl(my, j + 0); int n1 = __shfl(my, j + 1);
                int n2 = __shfl(my, j + 2); int n3 = __shfl(my, j + 3);
                float v0 = hs[(size_t)n0 * 64 + lane];
                float v1 = hs[(size_t)n1 * 64 + lane];
                float v2 = hs[(size_t)n2 * 64 + lane];
                float v3 = hs[(size_t)n3 * 64 + lane];
                acc += v0; acc2 += v1; acc += v2; acc2 += v3;
            }
            for (; j < cnt; ++j) {
                int nb = __shfl(my, j);
                acc += hs[(size_t)nb * 64 + lane];
            }
        }
    }
    agg[(size_t)node * 64 + lane] = acc + acc2;
}

// out = [X, A] @ W + B (optional relu); optionally hs_out = out * rs[row]
// fused in the epilogue (pre-scaled features for the next layer's gather).
// 256 threads -> 64x64 tile, 4x4 per-thread. LDS 64KB. X/A tiles XOR-swizzled.
template <bool RELU, bool WRITE_HS>
__global__ __launch_bounds__(256, 2) void gemm_cat_k(
    const float* X, const float* A,
    const float* __restrict__ W, const float* __restrict__ B,
    const float* __restrict__ rs, float* __restrict__ hs_out,
    float* out, int N) {
    __shared__ float sW[128 * 64];
    __shared__ float sX[64 * 64];
    __shared__ float sA[64 * 64];
    const int tid = threadIdx.x;

    for (int i = tid; i < 2048; i += 256) ((float4*)sW)[i] = ((const float4*)W)[i];

    const int row0 = blockIdx.x * 64;
    for (int i = tid; i < 1024; i += 256) {
        int r = i >> 4, c4 = (i & 15) << 2;
        int gr = row0 + r;
        float4 xv = make_float4(0.f, 0.f, 0.f, 0.f), av = xv;
        if (gr < N) {
            xv = ((const float4*)X)[(size_t)gr * 16 + (i & 15)];
            av = ((const float4*)A)[(size_t)gr * 16 + (i & 15)];
        }
        int sc = c4 ^ ((r & 12) << 1);
        *(float4*)&sX[(r << 6) + sc] = xv;
        *(float4*)&sA[(r << 6) + sc] = av;
    }
    __syncthreads();

    const int c0 = (tid & 15) << 2;
    const int r0 = (tid >> 4) << 2;
    const int sw = (r0 & 12) << 1;

    float4 bv = *(const float4*)(B + c0);
    float acc[4][4];
#pragma unroll
    for (int i = 0; i < 4; ++i) {
        acc[i][0] = bv.x; acc[i][1] = bv.y; acc[i][2] = bv.z; acc[i][3] = bv.w;
    }

#pragma unroll 8
    for (int k = 0; k < 64; ++k) {
        const int kx = k ^ sw;
        float4 w = *(const float4*)&sW[(k << 6) + c0];
        float a0 = sX[((r0 + 0) << 6) + kx];
        float a1 = sX[((r0 + 1) << 6) + kx];
        float a2 = sX[((r0 + 2) << 6) + kx];
        float a3 = sX[((r0 + 3) << 6) + kx];
        acc[0][0] = fmaf(a0, w.x, acc[0][0]); acc[0][1] = fmaf(a0, w.y, acc[0][1]);
        acc[0][2] = fmaf(a0, w.z, acc[0][2]); acc[0][3] = fmaf(a0, w.w, acc[0][3]);
        acc[1][0] = fmaf(a1, w.x, acc[1][0]); acc[1][1] = fmaf(a1, w.y, acc[1][1]);
        acc[1][2] = fmaf(a1, w.z, acc[1][2]); acc[1][3] = fmaf(a1, w.w, acc[1][3]);
        acc[2][0] = fmaf(a2, w.x, acc[2][0]); acc[2][1] = fmaf(a2, w.y, acc[2][1]);
        acc[2][2] = fmaf(a2, w.z, acc[2][2]); acc[2][3] = fmaf(a2, w.w, acc[2][3]);
        acc[3][0] = fmaf(a3, w.x, acc[3][0]); acc[3][1] = fmaf(a3, w.y, acc[3][1]);
        acc[3][2] = fmaf(a3, w.z, acc[3][2]); acc[3][3] = fmaf(a3, w.w, acc[3][3]);
    }
#pragma unroll 8
    for (int k = 0; k < 64; ++k) {
        const int kx = k ^ sw;
        float4 w = *(const float4*)&sW[((k + 64) << 6) + c0];
        float a0 = sA[((r0 + 0) << 6) + kx];
        float a1 = sA[((r0 + 1) << 6) + kx];
        float a2 = sA[((r0 + 2) << 6) + kx];
        float a3 = sA[((r0 + 3) << 6) + kx];
        acc[0][0] = fmaf(a0, w.x, acc[0][0]); acc[0][1] = fmaf(a0, w.y, acc[0][1]);
        acc[0][2] = fmaf(a0, w.z, acc[0][2]); acc[0][3] = fmaf(a0, w.w, acc[0][3]);
        acc[1][0] = fmaf(a1, w.x, acc[1][0]); acc[1][1] = fmaf(a1, w.y, acc[1][1]);
        acc[1][2] = fmaf(a1, w.z, acc[1][2]); acc[1][3] = fmaf(a1, w.w, acc[1][3]);
        acc[2][0] = fmaf(a2, w.x, acc[2][0]); acc[2][1] = fmaf(a2, w.y, acc[2][1]);
        acc[2][2] = fmaf(a2, w.z, acc[2][2]); acc[2][3] = fmaf(a2, w.w, acc[2][3]);
        acc[3][0] = fmaf(a3, w.x, acc[3][0]); acc[3][1] = fmaf(a3, w.y, acc[3][1]);
        acc[3][2] = fmaf(a3, w.z, acc[3][2]); acc[3][3] = fmaf(a3, w.w, acc[3][3]);
    }

#pragma unroll
    for (int i = 0; i < 4; ++i) {
        int gr = row0 + r0 + i;
        if (gr < N) {
            float4 o;
            o.x = RELU ? fmaxf(acc[i][0], 0.f) : acc[i][0];
            o.y = RELU ? fmaxf(acc[i][1], 0.f) : acc[i][1];
            o.z = RELU ? fmaxf(acc[i][2], 0.f) : acc[i][2];
            o.w = RELU ? fmaxf(acc[i][3], 0.f) : acc[i][3];
            *(float4*)(out + (size_t)gr * 64 + c0) = o;
            if (WRITE_HS) {
                float rr = rs[gr];
                float4 hsv = make_float4(o.x * rr, o.y * rr, o.z * rr, o.w * rr);
                *(float4*)(hs_out + (size_t)gr * 64 + c0) = hsv;
            }
        }
    }
}

extern "C" void kernel_launch(void* const* d_in, const int* in_sizes, int n_in,
                              void* d_out, int out_size, void* d_ws, size_t ws_size,
                              hipStream_t stream) {
    const float* x  = (const float*)d_in[0];
    const int* src  = (const int*)d_in[1];
    const int* dst  = (const int*)d_in[2];
    const float* W1 = (const float*)d_in[3];
    const float* b1 = (const float*)d_in[4];
    const float* W2 = (const float*)d_in[5];
    const float* b2 = (const float*)d_in[6];
    const float* W3 = (const float*)d_in[7];
    const float* b3 = (const float*)d_in[8];

    const int N = in_sizes[0] / 64;
    const int E = in_sizes[1];
    const int NB = (N + 127) >> 7;   // 128-node buckets (NB must be <= 1024)

    // workspace layout (~70 MB)
    float* bufH  = (float*)d_ws;                      // N*64 hidden (h1, h2)
    float* bufHS = bufH + (size_t)N * 64;             // N*64 pre-scaled features
    int* cnt_out = (int*)(bufHS + (size_t)N * 64);    // N
    int* cnt_in  = cnt_out + N;                       // N
    float* r_out = (float*)(cnt_in + N);              // N
    float* r_in  = r_out + N;                         // N
    float* r_und = r_in + N;                          // N
    int* ip_out  = (int*)(r_und + N);                 // N+1
    int* ip_in   = ip_out + (N + 1);                  // N+1
    int* bcnt_out = ip_in + (N + 1);                  // NB
    int* bcnt_in  = bcnt_out + NB;                    // NB
    int* bip_out  = bcnt_in + NB;                     // NB+1
    int* bip_in   = bip_out + (NB + 1);               // NB+1
    int* bcur_out = bip_in + (NB + 1);                // NB*16 (64B-padded)
    int* bcur_in  = bcur_out + NB * 16;               // NB*16
    unsigned* part_out = (unsigned*)(bcur_in + NB * 16); // E
    unsigned* part_in  = part_out + E;                   // E
    int* col_out = (int*)(part_in + E);               // E
    int* col_in  = col_out + E;                       // E

    float* aggB = (float*)d_out;   // aggregate buffer doubles as output

    const int TPB = 256;
    const int gE  = (E + TPB - 1) / TPB;
    const int gN  = (N + TPB - 1) / TPB;
    const int n4  = N * 16;
    const int g4  = (n4 + TPB - 1) / TPB;
    const int gAg = (int)(((size_t)N * 64 + TPB - 1) / TPB);
    const int gGm = (N + 63) / 64;

    // --- graph build: degrees -> buckets -> partition -> counting sort ---
    hipMemsetAsync(cnt_out, 0, 2 * (size_t)N * sizeof(int), stream);
    hist_k<<<gE, TPB, 0, stream>>>(src, dst, cnt_out, cnt_in, E);
    finalize_r_k<<<gN, TPB, 0, stream>>>(cnt_out, cnt_in, r_out, r_in, r_und, N);
    bucket_cnt_k<<<NB, 128, 0, stream>>>(cnt_out, cnt_in, bcnt_out, bcnt_in, N);
    bucket_scan_k<<<1, 1024, 0, stream>>>(bcnt_out, bcnt_in, bip_out, bip_in,
                                          bcur_out, bcur_in, NB);
    partition_k<<<gE, TPB, 0, stream>>>(src, dst, bcur_out, bcur_in,
                                        part_out, part_in, E);
    bucket_sort_k<<<dim3(NB, 2), TPB, 0, stream>>>(part_out, bip_out, part_in, bip_in,
                                                   ip_out, ip_in, col_out, col_in, N, E);

    // --- layer 1: 'O' — agg over in-edges of hs0 = x * r_out ---
    scale_rows_k<<<g4, TPB, 0, stream>>>(x, r_out, bufHS, n4);
    agg_k<<<gAg, TPB, 0, stream>>>(bufHS, ip_in, col_in, aggB, N);
    gemm_cat_k<true, true><<<gGm, TPB, 0, stream>>>(x, aggB, W1, b1, r_in, bufHS, bufH, N);

    // --- layer 2: 'I' — agg over out-edges of hs1 = h1 * r_in ---
    agg_k<<<gAg, TPB, 0, stream>>>(bufHS, ip_out, col_out, aggB, N);
    gemm_cat_k<true, true><<<gGm, TPB, 0, stream>>>(bufH, aggB, W2, b2, r_und, bufHS, bufH, N);

    // --- layer 3: 'U' — agg both directions of hs2 = h2 * r_und ---
    agg_dual_k<<<gAg, TPB, 0, stream>>>(bufHS, ip_in, col_in, ip_out, col_out, aggB, N);
    gemm_cat_k<false, false><<<gGm, TPB, 0, stream>>>(bufH, aggB, W3, b3, nullptr, nullptr,
                                                      (float*)d_out, N);
}

// Round 6
// 437.702 us; speedup vs baseline: 4.7684x; 1.2237x over previous
//
#include <hip/hip_runtime.h>

// ---------------------------------------------------------------------------
// 3-layer GraphSAGE (DGL GraphConv norm='left'), N=100k, E=1M, D=H=O=64, fp32.
// Round 6: partition rewritten with per-(block,bucket) RUN reservation:
// each block histograms its 2048-edge chunk in LDS (98 bins of 1024 nodes),
// reserves one contiguous run per bucket with a single atomicAdd, and
// scatters records into its own run -> all writes to a run come from one
// XCD, L2 assembles full lines (round-5 slot-granular cursors caused ~100MB
// of partial-line writebacks). bucket_sort uses 1024 bins to emit the CSR.
// Aggregation = wave-per-node CSR gather (8 loads in flight); GEMM = 64x64
// LDS tile, 4x4/thread, XOR-swizzled, next layer's scale fused in epilogue.
// ---------------------------------------------------------------------------

#define BSHIFT 10                 // 1024-node buckets
#define BMASK  ((1 << BSHIFT) - 1)
#define NBMAX  128                // max buckets (N <= 131072)
#define PCHUNK 2048               // edges per partition block

__global__ void hist_k(const int* __restrict__ src, const int* __restrict__ dst,
                       int* __restrict__ cnt_out, int* __restrict__ cnt_in, int E) {
    int t = blockIdx.x * blockDim.x + threadIdx.x;
    if (t < E) {
        atomicAdd(&cnt_out[src[t]], 1);
        atomicAdd(&cnt_in[dst[t]], 1);
    }
}

__global__ void finalize_r_k(const int* __restrict__ cnt_out, const int* __restrict__ cnt_in,
                             float* __restrict__ r_out, float* __restrict__ r_in,
                             float* __restrict__ r_und, int N) {
    int t = blockIdx.x * blockDim.x + threadIdx.x;
    if (t < N) {
        int a = cnt_out[t], b = cnt_in[t];
        r_out[t] = 1.0f / (float)(a < 1 ? 1 : a);
        r_in[t]  = 1.0f / (float)(b < 1 ? 1 : b);
        int c = a + b;
        r_und[t] = 1.0f / (float)(c < 1 ? 1 : c);
    }
}

// per-bucket edge counts (bucket = 1024 consecutive nodes)
__global__ void bucket_cnt_k(const int* __restrict__ cnt_out, const int* __restrict__ cnt_in,
                             int* __restrict__ bcnt_out, int* __restrict__ bcnt_in, int N) {
    __shared__ int s0[256], s1[256];
    int g = blockIdx.x, t = threadIdx.x;
    int a = 0, b = 0;
#pragma unroll
    for (int j = 0; j < 4; ++j) {
        int node = (g << BSHIFT) + t + (j << 8);
        if (node < N) { a += cnt_out[node]; b += cnt_in[node]; }
    }
    s0[t] = a; s1[t] = b;
    __syncthreads();
    for (int off = 128; off > 0; off >>= 1) {
        if (t < off) { s0[t] += s0[t + off]; s1[t] += s1[t + off]; }
        __syncthreads();
    }
    if (t == 0) { bcnt_out[g] = s0[0]; bcnt_in[g] = s1[0]; }
}

// single-block scan of bucket counts (NB <= 1024) -> bucket prefix + cursors
__global__ void bucket_scan_k(const int* __restrict__ bcnt_out, const int* __restrict__ bcnt_in,
                              int* __restrict__ bip_out, int* __restrict__ bip_in,
                              int* __restrict__ bcur_out, int* __restrict__ bcur_in, int NB) {
    __shared__ int s[1024];
    int t = threadIdx.x;
#pragma unroll 1
    for (int pass = 0; pass < 2; ++pass) {
        const int* bcnt = pass ? bcnt_in : bcnt_out;
        int* bip = pass ? bip_in : bip_out;
        int* bcur = pass ? bcur_in : bcur_out;
        int v = (t < NB) ? bcnt[t] : 0;
        s[t] = v; __syncthreads();
        for (int off = 1; off < 1024; off <<= 1) {
            int x = (t >= off) ? s[t - off] : 0;
            __syncthreads();
            s[t] += x;
            __syncthreads();
        }
        int excl = s[t] - v;
        if (t < NB) { bip[t] = excl; bcur[t] = excl; }
        if (t == NB) bip[NB] = excl;   // == E
        __syncthreads();
    }
}

// per-block run reservation partition: one contiguous run per (block,bucket),
// so every 64B line of part_* is written by a single XCD (except run edges).
// rec = (other_node << BSHIFT) | (local_node & BMASK)
__global__ __launch_bounds__(256) void partition_k(
    const int* __restrict__ src, const int* __restrict__ dst,
    int* __restrict__ bcur_out, int* __restrict__ bcur_in,
    unsigned* __restrict__ part_out, unsigned* __restrict__ part_in, int E) {
    __shared__ int sS[PCHUNK], sD[PCHUNK];
    __shared__ int hist[2][NBMAX];    // counts, then reused as local cursors
    __shared__ int gbase[2][NBMAX];
    const int t = threadIdx.x;
    const int e0 = blockIdx.x * PCHUNK;
    int n = E - e0; if (n > PCHUNK) n = PCHUNK;

    for (int i = t; i < NBMAX; i += 256) { hist[0][i] = 0; hist[1][i] = 0; }
    __syncthreads();
    for (int i = t; i < n; i += 256) {
        int s = src[e0 + i], d = dst[e0 + i];
        sS[i] = s; sD[i] = d;
        atomicAdd(&hist[0][d >> BSHIFT], 1);   // in-partition binned by dst
        atomicAdd(&hist[1][s >> BSHIFT], 1);   // out-partition binned by src
    }
    __syncthreads();
    if (t < NBMAX) {
        int c = hist[0][t];
        gbase[0][t] = c ? atomicAdd(&bcur_in[t], c) : 0;
        hist[0][t] = 0;
    } else {
        int b = t - NBMAX;
        int c = hist[1][b];
        gbase[1][b] = c ? atomicAdd(&bcur_out[b], c) : 0;
        hist[1][b] = 0;
    }
    __syncthreads();
    for (int i = t; i < n; i += 256) {
        int s = sS[i], d = sD[i];
        int bi = d >> BSHIFT;
        int p = gbase[0][bi] + atomicAdd(&hist[0][bi], 1);
        part_in[p] = ((unsigned)s << BSHIFT) | (unsigned)(d & BMASK);
        int bo = s >> BSHIFT;
        int q = gbase[1][bo] + atomicAdd(&hist[1][bo], 1);
        part_out[q] = ((unsigned)d << BSHIFT) | (unsigned)(s & BMASK);
    }
}

// one block per (bucket, direction): counting-sort the bucket's records by
// local node id (1024 bins). Emits per-node CSR pointers ip[] and col[].
// All record reads + col writes stay inside the bucket's L2-resident window.
__global__ __launch_bounds__(256) void bucket_sort_k(
    const unsigned* __restrict__ pa, const int* __restrict__ bipa,
    const unsigned* __restrict__ pb, const int* __restrict__ bipb,
    int* __restrict__ ipa, int* __restrict__ ipb,
    int* __restrict__ cola, int* __restrict__ colb, int N, int E) {
    const unsigned* part = blockIdx.y ? pb : pa;
    const int* bip = blockIdx.y ? bipb : bipa;
    int* ip  = blockIdx.y ? ipb : ipa;
    int* col = blockIdx.y ? colb : cola;
    __shared__ int cnt[1024];
    __shared__ int ps[256];
    const int g = blockIdx.x, t = threadIdx.x;
    const int b = bip[g], e = bip[g + 1];

    for (int i = t; i < 1024; i += 256) cnt[i] = 0;
    __syncthreads();
    for (int i = b + t; i < e; i += 256) atomicAdd(&cnt[part[i] & (unsigned)BMASK], 1);
    __syncthreads();

    int c0 = cnt[4 * t + 0], c1 = cnt[4 * t + 1], c2 = cnt[4 * t + 2], c3 = cnt[4 * t + 3];
    int tot = c0 + c1 + c2 + c3;
    ps[t] = tot;
    __syncthreads();
    for (int off = 1; off < 256; off <<= 1) {
        int v = (t >= off) ? ps[t - off] : 0;
        __syncthreads();
        ps[t] += v;
        __syncthreads();
    }
    int base = b + ps[t] - tot;
    int node0 = (g << BSHIFT) + 4 * t;
    int cc[4] = {c0, c1, c2, c3};
#pragma unroll
    for (int j = 0; j < 4; ++j) {
        cnt[4 * t + j] = base;           // becomes the fill cursor
        int node = node0 + j;
        if (node < N) ip[node] = base;
        base += cc[j];
    }
    if (g == 0 && t == 0) ip[N] = E;
    __syncthreads();
    for (int i = b + t; i < e; i += 256) {
        unsigned rec = part[i];
        int p = atomicAdd(&cnt[rec & (unsigned)BMASK], 1);
        col[p] = (int)(rec >> BSHIFT);
    }
}

// hs[row] = in[row] * r[row] (float4)
__global__ void scale_rows_k(const float* __restrict__ in, const float* __restrict__ r,
                             float* __restrict__ out, int n4) {
    int t = blockIdx.x * blockDim.x + threadIdx.x;
    if (t < n4) {
        float s = r[t >> 4];
        float4 v = ((const float4*)in)[t];
        v.x *= s; v.y *= s; v.z *= s; v.w *= s;
        ((float4*)out)[t] = v;
    }
}

// one wave per node; lane = feature. agg[n][f] = sum_{nb} hs[nb][f]
// col ids loaded 64-at-a-time coalesced, broadcast via shuffle; 8 independent
// row-gathers in flight per unroll group.
__global__ void agg_k(const float* __restrict__ hs, const int* __restrict__ ip,
                      const int* __restrict__ col, float* __restrict__ agg, int N) {
    int node = (blockIdx.x * blockDim.x + threadIdx.x) >> 6;
    int lane = threadIdx.x & 63;
    if (node >= N) return;
    int b = ip[node], e = ip[node + 1];
    float acc = 0.f, acc2 = 0.f;
    for (int base = b; base < e; base += 64) {
        int cnt = e - base; if (cnt > 64) cnt = 64;
        int my = (lane < cnt) ? col[base + lane] : 0;
        int j = 0;
        for (; j + 8 <= cnt; j += 8) {
            int n0 = __shfl(my, j + 0); int n1 = __shfl(my, j + 1);
            int n2 = __shfl(my, j + 2); int n3 = __shfl(my, j + 3);
            int n4 = __shfl(my, j + 4); int n5 = __shfl(my, j + 5);
            int n6 = __shfl(my, j + 6); int n7 = __shfl(my, j + 7);
            float v0 = hs[(size_t)n0 * 64 + lane];
            float v1 = hs[(size_t)n1 * 64 + lane];
            float v2 = hs[(size_t)n2 * 64 + lane];
            float v3 = hs[(size_t)n3 * 64 + lane];
            float v4 = hs[(size_t)n4 * 64 + lane];
            float v5 = hs[(size_t)n5 * 64 + lane];
            float v6 = hs[(size_t)n6 * 64 + lane];
            float v7 = hs[(size_t)n7 * 64 + lane];
            acc += v0; acc2 += v1; acc += v2; acc2 += v3;
            acc += v4; acc2 += v5; acc += v6; acc2 += v7;
        }
        for (; j + 4 <= cnt; j += 4) {
            int n0 = __shfl(my, j + 0); int n1 = __shfl(my, j + 1);
            int n2 = __shfl(my, j + 2); int n3 = __shfl(my, j + 3);
            float v0 = hs[(size_t)n0 * 64 + lane];
            float v1 = hs[(size_t)n1 * 64 + lane];
            float v2 = hs[(size_t)n2 * 64 + lane];
            float v3 = hs[(size_t)n3 * 64 + lane];
            acc += v0; acc2 += v1; acc += v2; acc2 += v3;
        }
        for (; j < cnt; ++j) {
            int nb = __shfl(my, j);
            acc += hs[(size_t)nb * 64 + lane];
        }
    }
    agg[(size_t)node * 64 + lane] = acc + acc2;
}

__global__ void agg_dual_k(const float* __restrict__ hs,
                           const int* __restrict__ ipA, const int* __restrict__ colA,
                           const int* __restrict__ ipB, const int* __restrict__ colB,
                           float* __restrict__ agg, int N) {
    int node = (blockIdx.x * blockDim.x + threadIdx.x) >> 6;
    int lane = threadIdx.x & 63;
    if (node >= N) return;
    float acc = 0.f, acc2 = 0.f;
#pragma unroll 1
    for (int pass = 0; pass < 2; ++pass) {
        const int* ip  = pass ? ipB : ipA;
        const int* col = pass ? colB : colA;
        int b = ip[node], e = ip[node + 1];
        for (int base = b; base < e; base += 64) {
            int cnt = e - base; if (cnt > 64) cnt = 64;
            int my = (lane < cnt) ? col[base + lane] : 0;
            int j = 0;
            for (; j + 8 <= cnt; j += 8) {
                int n0 = __shfl(my, j + 0); int n1 = __shfl(my, j + 1);
                int n2 = __shfl(my, j + 2); int n3 = __shfl(my, j + 3);
                int n4 = __shfl(my, j + 4); int n5 = __shfl(my, j + 5);
                int n6 = __shfl(my, j + 6); int n7 = __shfl(my, j + 7);
                float v0 = hs[(size_t)n0 * 64 + lane];
                float v1 = hs[(size_t)n1 * 64 + lane];
                float v2 = hs[(size_t)n2 * 64 + lane];
                float v3 = hs[(size_t)n3 * 64 + lane];
                float v4 = hs[(size_t)n4 * 64 + lane];
                float v5 = hs[(size_t)n5 * 64 + lane];
                float v6 = hs[(size_t)n6 * 64 + lane];
                float v7 = hs[(size_t)n7 * 64 + lane];
                acc += v0; acc2 += v1; acc += v2; acc2 += v3;
                acc += v4; acc2 += v5; acc += v6; acc2 += v7;
            }
            for (; j + 4 <= cnt; j += 4) {
                int n0 = __shfl(my, j + 0); int n1 = __shfl(my, j + 1);
                int n2 = __shfl(my, j + 2); int n3 = __shfl(my, j + 3);
                float v0 = hs[(size_t)n0 * 64 + lane];
                float v1 = hs[(size_t)n1 * 64 + lane];
                float v2 = hs[(size_t)n2 * 64 + lane];
                float v3 = hs[(size_t)n3 * 64 + lane];
                acc += v0; acc2 += v1; acc += v2; acc2 += v3;
            }
            for (; j < cnt; ++j) {
                int nb = __shfl(my, j);
                acc += hs[(size_t)nb * 64 + lane];
            }
        }
    }
    agg[(size_t)node * 64 + lane] = acc + acc2;
}

// out = [X, A] @ W + B (optional relu); optionally hs_out = out * rs[row]
// fused in the epilogue (pre-scaled features for the next layer's gather).
// 256 threads -> 64x64 tile, 4x4 per-thread. LDS 64KB. X/A tiles XOR-swizzled.
template <bool RELU, bool WRITE_HS>
__global__ __launch_bounds__(256, 2) void gemm_cat_k(
    const float* X, const float* A,
    const float* __restrict__ W, const float* __restrict__ B,
    const float* __restrict__ rs, float* __restrict__ hs_out,
    float* out, int N) {
    __shared__ float sW[128 * 64];
    __shared__ float sX[64 * 64];
    __shared__ float sA[64 * 64];
    const int tid = threadIdx.x;

    for (int i = tid; i < 2048; i += 256) ((float4*)sW)[i] = ((const float4*)W)[i];

    const int row0 = blockIdx.x * 64;
    for (int i = tid; i < 1024; i += 256) {
        int r = i >> 4, c4 = (i & 15) << 2;
        int gr = row0 + r;
        float4 xv = make_float4(0.f, 0.f, 0.f, 0.f), av = xv;
        if (gr < N) {
            xv = ((const float4*)X)[(size_t)gr * 16 + (i & 15)];
            av = ((const float4*)A)[(size_t)gr * 16 + (i & 15)];
        }
        int sc = c4 ^ ((r & 12) << 1);
        *(float4*)&sX[(r << 6) + sc] = xv;
        *(float4*)&sA[(r << 6) + sc] = av;
    }
    __syncthreads();

    const int c0 = (tid & 15) << 2;
    const int r0 = (tid >> 4) << 2;
    const int sw = (r0 & 12) << 1;

    float4 bv = *(const float4*)(B + c0);
    float acc[4][4];
#pragma unroll
    for (int i = 0; i < 4; ++i) {
        acc[i][0] = bv.x; acc[i][1] = bv.y; acc[i][2] = bv.z; acc[i][3] = bv.w;
    }

#pragma unroll 8
    for (int k = 0; k < 64; ++k) {
        const int kx = k ^ sw;
        float4 w = *(const float4*)&sW[(k << 6) + c0];
        float a0 = sX[((r0 + 0) << 6) + kx];
        float a1 = sX[((r0 + 1) << 6) + kx];
        float a2 = sX[((r0 + 2) << 6) + kx];
        float a3 = sX[((r0 + 3) << 6) + kx];
        acc[0][0] = fmaf(a0, w.x, acc[0][0]); acc[0][1] = fmaf(a0, w.y, acc[0][1]);
        acc[0][2] = fmaf(a0, w.z, acc[0][2]); acc[0][3] = fmaf(a0, w.w, acc[0][3]);
        acc[1][0] = fmaf(a1, w.x, acc[1][0]); acc[1][1] = fmaf(a1, w.y, acc[1][1]);
        acc[1][2] = fmaf(a1, w.z, acc[1][2]); acc[1][3] = fmaf(a1, w.w, acc[1][3]);
        acc[2][0] = fmaf(a2, w.x, acc[2][0]); acc[2][1] = fmaf(a2, w.y, acc[2][1]);
        acc[2][2] = fmaf(a2, w.z, acc[2][2]); acc[2][3] = fmaf(a2, w.w, acc[2][3]);
        acc[3][0] = fmaf(a3, w.x, acc[3][0]); acc[3][1] = fmaf(a3, w.y, acc[3][1]);
        acc[3][2] = fmaf(a3, w.z, acc[3][2]); acc[3][3] = fmaf(a3, w.w, acc[3][3]);
    }
#pragma unroll 8
    for (int k = 0; k < 64; ++k) {
        const int kx = k ^ sw;
        float4 w = *(const float4*)&sW[((k + 64) << 6) + c0];
        float a0 = sA[((r0 + 0) << 6) + kx];
        float a1 = sA[((r0 + 1) << 6) + kx];
        float a2 = sA[((r0 + 2) << 6) + kx];
        float a3 = sA[((r0 + 3) << 6) + kx];
        acc[0][0] = fmaf(a0, w.x, acc[0][0]); acc[0][1] = fmaf(a0, w.y, acc[0][1]);
        acc[0][2] = fmaf(a0, w.z, acc[0][2]); acc[0][3] = fmaf(a0, w.w, acc[0][3]);
        acc[1][0] = fmaf(a1, w.x, acc[1][0]); acc[1][1] = fmaf(a1, w.y, acc[1][1]);
        acc[1][2] = fmaf(a1, w.z, acc[1][2]); acc[1][3] = fmaf(a1, w.w, acc[1][3]);
        acc[2][0] = fmaf(a2, w.x, acc[2][0]); acc[2][1] = fmaf(a2, w.y, acc[2][1]);
        acc[2][2] = fmaf(a2, w.z, acc[2][2]); acc[2][3] = fmaf(a2, w.w, acc[2][3]);
        acc[3][0] = fmaf(a3, w.x, acc[3][0]); acc[3][1] = fmaf(a3, w.y, acc[3][1]);
        acc[3][2] = fmaf(a3, w.z, acc[3][2]); acc[3][3] = fmaf(a3, w.w, acc[3][3]);
    }

#pragma unroll
    for (int i = 0; i < 4; ++i) {
        int gr = row0 + r0 + i;
        if (gr < N) {
            float4 o;
            o.x = RELU ? fmaxf(acc[i][0], 0.f) : acc[i][0];
            o.y = RELU ? fmaxf(acc[i][1], 0.f) : acc[i][1];
            o.z = RELU ? fmaxf(acc[i][2], 0.f) : acc[i][2];
            o.w = RELU ? fmaxf(acc[i][3], 0.f) : acc[i][3];
            *(float4*)(out + (size_t)gr * 64 + c0) = o;
            if (WRITE_HS) {
                float rr = rs[gr];
                float4 hsv = make_float4(o.x * rr, o.y * rr, o.z * rr, o.w * rr);
                *(float4*)(hs_out + (size_t)gr * 64 + c0) = hsv;
            }
        }
    }
}

extern "C" void kernel_launch(void* const* d_in, const int* in_sizes, int n_in,
                              void* d_out, int out_size, void* d_ws, size_t ws_size,
                              hipStream_t stream) {
    const float* x  = (const float*)d_in[0];
    const int* src  = (const int*)d_in[1];
    const int* dst  = (const int*)d_in[2];
    const float* W1 = (const float*)d_in[3];
    const float* b1 = (const float*)d_in[4];
    const float* W2 = (const float*)d_in[5];
    const float* b2 = (const float*)d_in[6];
    const float* W3 = (const float*)d_in[7];
    const float* b3 = (const float*)d_in[8];

    const int N = in_sizes[0] / 64;
    const int E = in_sizes[1];
    const int NB = (N + BMASK) >> BSHIFT;   // 1024-node buckets (NB <= 128)

    // workspace layout (~70 MB)
    float* bufH  = (float*)d_ws;                      // N*64 hidden (h1, h2)
    float* bufHS = bufH + (size_t)N * 64;             // N*64 pre-scaled features
    int* cnt_out = (int*)(bufHS + (size_t)N * 64);    // N
    int* cnt_in  = cnt_out + N;                       // N
    float* r_out = (float*)(cnt_in + N);              // N
    float* r_in  = r_out + N;                         // N
    float* r_und = r_in + N;                          // N
    int* ip_out  = (int*)(r_und + N);                 // N+1
    int* ip_in   = ip_out + (N + 1);                  // N+1
    int* bcnt_out = ip_in + (N + 1);                  // NB
    int* bcnt_in  = bcnt_out + NB;                    // NB
    int* bip_out  = bcnt_in + NB;                     // NB+1
    int* bip_in   = bip_out + (NB + 1);               // NB+1
    int* bcur_out = bip_in + (NB + 1);                // NB
    int* bcur_in  = bcur_out + NB;                    // NB
    unsigned* part_out = (unsigned*)(bcur_in + NB);   // E
    unsigned* part_in  = part_out + E;                // E
    int* col_out = (int*)(part_in + E);               // E
    int* col_in  = col_out + E;                       // E

    float* aggB = (float*)d_out;   // aggregate buffer doubles as output

    const int TPB = 256;
    const int gE  = (E + TPB - 1) / TPB;
    const int gN  = (N + TPB - 1) / TPB;
    const int n4  = N * 16;
    const int g4  = (n4 + TPB - 1) / TPB;
    const int gAg = (int)(((size_t)N * 64 + TPB - 1) / TPB);
    const int gGm = (N + 63) / 64;
    const int gP  = (E + PCHUNK - 1) / PCHUNK;

    // --- graph build: degrees -> buckets -> run-reserved partition -> sort ---
    hipMemsetAsync(cnt_out, 0, 2 * (size_t)N * sizeof(int), stream);
    hist_k<<<gE, TPB, 0, stream>>>(src, dst, cnt_out, cnt_in, E);
    finalize_r_k<<<gN, TPB, 0, stream>>>(cnt_out, cnt_in, r_out, r_in, r_und, N);
    bucket_cnt_k<<<NB, TPB, 0, stream>>>(cnt_out, cnt_in, bcnt_out, bcnt_in, N);
    bucket_scan_k<<<1, 1024, 0, stream>>>(bcnt_out, bcnt_in, bip_out, bip_in,
                                          bcur_out, bcur_in, NB);
    partition_k<<<gP, TPB, 0, stream>>>(src, dst, bcur_out, bcur_in,
                                        part_out, part_in, E);
    bucket_sort_k<<<dim3(NB, 2), TPB, 0, stream>>>(part_out, bip_out, part_in, bip_in,
                                                   ip_out, ip_in, col_out, col_in, N, E);

    // --- layer 1: 'O' — agg over in-edges of hs0 = x * r_out ---
    scale_rows_k<<<g4, TPB, 0, stream>>>(x, r_out, bufHS, n4);
    agg_k<<<gAg, TPB, 0, stream>>>(bufHS, ip_in, col_in, aggB, N);
    gemm_cat_k<true, true><<<gGm, TPB, 0, stream>>>(x, aggB, W1, b1, r_in, bufHS, bufH, N);

    // --- layer 2: 'I' — agg over out-edges of hs1 = h1 * r_in ---
    agg_k<<<gAg, TPB, 0, stream>>>(bufHS, ip_out, col_out, aggB, N);
    gemm_cat_k<true, true><<<gGm, TPB, 0, stream>>>(bufH, aggB, W2, b2, r_und, bufHS, bufH, N);

    // --- layer 3: 'U' — agg both directions of hs2 = h2 * r_und ---
    agg_dual_k<<<gAg, TPB, 0, stream>>>(bufHS, ip_in, col_in, ip_out, col_out, aggB, N);
    gemm_cat_k<false, false><<<gGm, TPB, 0, stream>>>(bufH, aggB, W3, b3, nullptr, nullptr,
                                                      (float*)d_out, N);
}

// Round 7
// 365.753 us; speedup vs baseline: 5.7064x; 1.1967x over previous
//
#include <hip/hip_runtime.h>

// ---------------------------------------------------------------------------
// 3-layer GraphSAGE (DGL GraphConv norm='left'), N=100k, E=1M, D=H=O=64, fp32.
// Round 7:
//  * hist_k (2M random device atomics, 62MB writeback) DELETED. Per-bucket
//    edge totals now come from a chunked LDS histogram (bucket_hist_k);
//    per-node degrees fall out of bucket_sort_k's counting-sort bins (deg_*),
//    finalize_r runs after the sort on coalesced deg arrays.
//  * agg gather widened: 4 rows per wave, 16 lanes x float4 per row
//    (4x fewer load instructions, 4x bytes/lane in flight), cross-group
//    shuffle reduce, quarter-wave float4 writeout.
//  * partition keeps round-6 per-(block,bucket) run reservation (one XCD
//    owns each run -> full-line L2 writebacks).
// ---------------------------------------------------------------------------

#define BSHIFT 10                 // 1024-node buckets
#define BMASK  ((1 << BSHIFT) - 1)
#define NBMAX  128                // max buckets (N <= 131072)
#define PCHUNK 2048               // edges per partition block
#define HCHUNK 4096               // edges per bucket-hist block

// chunked LDS histogram of edges into buckets (both directions)
__global__ __launch_bounds__(256) void bucket_hist_k(
    const int* __restrict__ src, const int* __restrict__ dst,
    int* __restrict__ bcnt_out, int* __restrict__ bcnt_in, int E) {
    __shared__ int h0[NBMAX], h1[NBMAX];
    const int t = threadIdx.x;
    const int e0 = blockIdx.x * HCHUNK;
    int n = E - e0; if (n > HCHUNK) n = HCHUNK;
    for (int i = t; i < NBMAX; i += 256) { h0[i] = 0; h1[i] = 0; }
    __syncthreads();
    for (int i = t; i < n; i += 256) {
        atomicAdd(&h0[src[e0 + i] >> BSHIFT], 1);
        atomicAdd(&h1[dst[e0 + i] >> BSHIFT], 1);
    }
    __syncthreads();
    if (t < NBMAX) {
        int c = h0[t];
        if (c) atomicAdd(&bcnt_out[t], c);
    } else {
        int b = t - NBMAX;
        int c = h1[b];
        if (c) atomicAdd(&bcnt_in[b], c);
    }
}

// r arrays from the degree arrays emitted by bucket_sort_k
__global__ void finalize_r_k(const int* __restrict__ deg_out, const int* __restrict__ deg_in,
                             float* __restrict__ r_out, float* __restrict__ r_in,
                             float* __restrict__ r_und, int N) {
    int t = blockIdx.x * blockDim.x + threadIdx.x;
    if (t < N) {
        int a = deg_out[t], b = deg_in[t];
        r_out[t] = 1.0f / (float)(a < 1 ? 1 : a);
        r_in[t]  = 1.0f / (float)(b < 1 ? 1 : b);
        int c = a + b;
        r_und[t] = 1.0f / (float)(c < 1 ? 1 : c);
    }
}

// single-block scan of bucket counts (NB <= 1024) -> bucket prefix + cursors
__global__ void bucket_scan_k(const int* __restrict__ bcnt_out, const int* __restrict__ bcnt_in,
                              int* __restrict__ bip_out, int* __restrict__ bip_in,
                              int* __restrict__ bcur_out, int* __restrict__ bcur_in, int NB) {
    __shared__ int s[1024];
    int t = threadIdx.x;
#pragma unroll 1
    for (int pass = 0; pass < 2; ++pass) {
        const int* bcnt = pass ? bcnt_in : bcnt_out;
        int* bip = pass ? bip_in : bip_out;
        int* bcur = pass ? bcur_in : bcur_out;
        int v = (t < NB) ? bcnt[t] : 0;
        s[t] = v; __syncthreads();
        for (int off = 1; off < 1024; off <<= 1) {
            int x = (t >= off) ? s[t - off] : 0;
            __syncthreads();
            s[t] += x;
            __syncthreads();
        }
        int excl = s[t] - v;
        if (t < NB) { bip[t] = excl; bcur[t] = excl; }
        if (t == NB) bip[NB] = excl;   // == E
        __syncthreads();
    }
}

// per-block run reservation partition: one contiguous run per (block,bucket),
// so every 64B line of part_* is written by a single XCD (except run edges).
// rec = (other_node << BSHIFT) | (local_node & BMASK)
__global__ __launch_bounds__(256) void partition_k(
    const int* __restrict__ src, const int* __restrict__ dst,
    int* __restrict__ bcur_out, int* __restrict__ bcur_in,
    unsigned* __restrict__ part_out, unsigned* __restrict__ part_in, int E) {
    __shared__ int sS[PCHUNK], sD[PCHUNK];
    __shared__ int hist[2][NBMAX];    // counts, then reused as local cursors
    __shared__ int gbase[2][NBMAX];
    const int t = threadIdx.x;
    const int e0 = blockIdx.x * PCHUNK;
    int n = E - e0; if (n > PCHUNK) n = PCHUNK;

    for (int i = t; i < NBMAX; i += 256) { hist[0][i] = 0; hist[1][i] = 0; }
    __syncthreads();
    for (int i = t; i < n; i += 256) {
        int s = src[e0 + i], d = dst[e0 + i];
        sS[i] = s; sD[i] = d;
        atomicAdd(&hist[0][d >> BSHIFT], 1);   // in-partition binned by dst
        atomicAdd(&hist[1][s >> BSHIFT], 1);   // out-partition binned by src
    }
    __syncthreads();
    if (t < NBMAX) {
        int c = hist[0][t];
        gbase[0][t] = c ? atomicAdd(&bcur_in[t], c) : 0;
        hist[0][t] = 0;
    } else {
        int b = t - NBMAX;
        int c = hist[1][b];
        gbase[1][b] = c ? atomicAdd(&bcur_out[b], c) : 0;
        hist[1][b] = 0;
    }
    __syncthreads();
    for (int i = t; i < n; i += 256) {
        int s = sS[i], d = sD[i];
        int bi = d >> BSHIFT;
        int p = gbase[0][bi] + atomicAdd(&hist[0][bi], 1);
        part_in[p] = ((unsigned)s << BSHIFT) | (unsigned)(d & BMASK);
        int bo = s >> BSHIFT;
        int q = gbase[1][bo] + atomicAdd(&hist[1][bo], 1);
        part_out[q] = ((unsigned)d << BSHIFT) | (unsigned)(s & BMASK);
    }
}

// one block per (bucket, direction): counting-sort the bucket's records by
// local node id (1024 bins). Emits CSR pointers ip[], degrees deg[], col[].
__global__ __launch_bounds__(256) void bucket_sort_k(
    const unsigned* __restrict__ pa, const int* __restrict__ bipa,
    const unsigned* __restrict__ pb, const int* __restrict__ bipb,
    int* __restrict__ ipa, int* __restrict__ ipb,
    int* __restrict__ cola, int* __restrict__ colb,
    int* __restrict__ dega, int* __restrict__ degb, int N, int E) {
    const unsigned* part = blockIdx.y ? pb : pa;
    const int* bip = blockIdx.y ? bipb : bipa;
    int* ip  = blockIdx.y ? ipb : ipa;
    int* col = blockIdx.y ? colb : cola;
    int* deg = blockIdx.y ? degb : dega;
    __shared__ int cnt[1024];
    __shared__ int ps[256];
    const int g = blockIdx.x, t = threadIdx.x;
    const int b = bip[g], e = bip[g + 1];

    for (int i = t; i < 1024; i += 256) cnt[i] = 0;
    __syncthreads();
    for (int i = b + t; i < e; i += 256) atomicAdd(&cnt[part[i] & (unsigned)BMASK], 1);
    __syncthreads();

    int c0 = cnt[4 * t + 0], c1 = cnt[4 * t + 1], c2 = cnt[4 * t + 2], c3 = cnt[4 * t + 3];
    int tot = c0 + c1 + c2 + c3;
    ps[t] = tot;
    __syncthreads();
    for (int off = 1; off < 256; off <<= 1) {
        int v = (t >= off) ? ps[t - off] : 0;
        __syncthreads();
        ps[t] += v;
        __syncthreads();
    }
    int base = b + ps[t] - tot;
    int node0 = (g << BSHIFT) + 4 * t;
    int cc[4] = {c0, c1, c2, c3};
#pragma unroll
    for (int j = 0; j < 4; ++j) {
        cnt[4 * t + j] = base;           // becomes the fill cursor
        int node = node0 + j;
        if (node < N) { ip[node] = base; deg[node] = cc[j]; }
        base += cc[j];
    }
    if (g == 0 && t == 0) ip[N] = E;
    __syncthreads();
    for (int i = b + t; i < e; i += 256) {
        unsigned rec = part[i];
        int p = atomicAdd(&cnt[rec & (unsigned)BMASK], 1);
        col[p] = (int)(rec >> BSHIFT);
    }
}

// hs[row] = in[row] * r[row] (float4)
__global__ void scale_rows_k(const float* __restrict__ in, const float* __restrict__ r,
                             float* __restrict__ out, int n4) {
    int t = blockIdx.x * blockDim.x + threadIdx.x;
    if (t < n4) {
        float s = r[t >> 4];
        float4 v = ((const float4*)in)[t];
        v.x *= s; v.y *= s; v.z *= s; v.w *= s;
        ((float4*)out)[t] = v;
    }
}

// one wave per node; 4 neighbor rows processed concurrently, 16 lanes x
// float4 per row (coalesced 256B per group). Clamped over-reads hit the
// just-fetched row -> L1/L2 hot, negligible. Cross-group shuffle reduce,
// quarter-wave float4 writeout.
__device__ __forceinline__ void agg_list(const float* __restrict__ hs,
                                         const int* __restrict__ col,
                                         int b, int e, int lane, int grp, int fo,
                                         float4& acc) {
    for (int base = b; base < e; base += 64) {
        int cnt = e - base; if (cnt > 64) cnt = 64;
        int my = (lane < cnt) ? col[base + lane] : 0;
        for (int j = 0; j < cnt; j += 8) {
            int i0 = j + grp, i1 = j + 4 + grp;
            int n0 = __shfl(my, i0 < cnt ? i0 : cnt - 1);
            int n1 = __shfl(my, i1 < cnt ? i1 : cnt - 1);
            float4 v0 = *(const float4*)(hs + (size_t)n0 * 64 + (fo << 2));
            float4 v1 = *(const float4*)(hs + (size_t)n1 * 64 + (fo << 2));
            if (i0 < cnt) { acc.x += v0.x; acc.y += v0.y; acc.z += v0.z; acc.w += v0.w; }
            if (i1 < cnt) { acc.x += v1.x; acc.y += v1.y; acc.z += v1.z; acc.w += v1.w; }
        }
    }
}

__global__ void agg_k(const float* __restrict__ hs, const int* __restrict__ ip,
                      const int* __restrict__ col, float* __restrict__ agg, int N) {
    int node = (blockIdx.x * blockDim.x + threadIdx.x) >> 6;
    int lane = threadIdx.x & 63;
    if (node >= N) return;
    const int grp = lane >> 4, fo = lane & 15;
    float4 acc = make_float4(0.f, 0.f, 0.f, 0.f);
    agg_list(hs, col, ip[node], ip[node + 1], lane, grp, fo, acc);
    acc.x += __shfl_xor(acc.x, 16); acc.y += __shfl_xor(acc.y, 16);
    acc.z += __shfl_xor(acc.z, 16); acc.w += __shfl_xor(acc.w, 16);
    acc.x += __shfl_xor(acc.x, 32); acc.y += __shfl_xor(acc.y, 32);
    acc.z += __shfl_xor(acc.z, 32); acc.w += __shfl_xor(acc.w, 32);
    if (lane < 16) ((float4*)(agg + (size_t)node * 64))[fo] = acc;
}

__global__ void agg_dual_k(const float* __restrict__ hs,
                           const int* __restrict__ ipA, const int* __restrict__ colA,
                           const int* __restrict__ ipB, const int* __restrict__ colB,
                           float* __restrict__ agg, int N) {
    int node = (blockIdx.x * blockDim.x + threadIdx.x) >> 6;
    int lane = threadIdx.x & 63;
    if (node >= N) return;
    const int grp = lane >> 4, fo = lane & 15;
    float4 acc = make_float4(0.f, 0.f, 0.f, 0.f);
    agg_list(hs, colA, ipA[node], ipA[node + 1], lane, grp, fo, acc);
    agg_list(hs, colB, ipB[node], ipB[node + 1], lane, grp, fo, acc);
    acc.x += __shfl_xor(acc.x, 16); acc.y += __shfl_xor(acc.y, 16);
    acc.z += __shfl_xor(acc.z, 16); acc.w += __shfl_xor(acc.w, 16);
    acc.x += __shfl_xor(acc.x, 32); acc.y += __shfl_xor(acc.y, 32);
    acc.z += __shfl_xor(acc.z, 32); acc.w += __shfl_xor(acc.w, 32);
    if (lane < 16) ((float4*)(agg + (size_t)node * 64))[fo] = acc;
}

// out = [X, A] @ W + B (optional relu); optionally hs_out = out * rs[row]
// fused in the epilogue (pre-scaled features for the next layer's gather).
// 256 threads -> 64x64 tile, 4x4 per-thread. LDS 64KB. X/A tiles XOR-swizzled.
template <bool RELU, bool WRITE_HS>
__global__ __launch_bounds__(256, 2) void gemm_cat_k(
    const float* X, const float* A,
    const float* __restrict__ W, const float* __restrict__ B,
    const float* __restrict__ rs, float* __restrict__ hs_out,
    float* out, int N) {
    __shared__ float sW[128 * 64];
    __shared__ float sX[64 * 64];
    __shared__ float sA[64 * 64];
    const int tid = threadIdx.x;

    for (int i = tid; i < 2048; i += 256) ((float4*)sW)[i] = ((const float4*)W)[i];

    const int row0 = blockIdx.x * 64;
    for (int i = tid; i < 1024; i += 256) {
        int r = i >> 4, c4 = (i & 15) << 2;
        int gr = row0 + r;
        float4 xv = make_float4(0.f, 0.f, 0.f, 0.f), av = xv;
        if (gr < N) {
            xv = ((const float4*)X)[(size_t)gr * 16 + (i & 15)];
            av = ((const float4*)A)[(size_t)gr * 16 + (i & 15)];
        }
        int sc = c4 ^ ((r & 12) << 1);
        *(float4*)&sX[(r << 6) + sc] = xv;
        *(float4*)&sA[(r << 6) + sc] = av;
    }
    __syncthreads();

    const int c0 = (tid & 15) << 2;
    const int r0 = (tid >> 4) << 2;
    const int sw = (r0 & 12) << 1;

    float4 bv = *(const float4*)(B + c0);
    float acc[4][4];
#pragma unroll
    for (int i = 0; i < 4; ++i) {
        acc[i][0] = bv.x; acc[i][1] = bv.y; acc[i][2] = bv.z; acc[i][3] = bv.w;
    }

#pragma unroll 8
    for (int k = 0; k < 64; ++k) {
        const int kx = k ^ sw;
        float4 w = *(const float4*)&sW[(k << 6) + c0];
        float a0 = sX[((r0 + 0) << 6) + kx];
        float a1 = sX[((r0 + 1) << 6) + kx];
        float a2 = sX[((r0 + 2) << 6) + kx];
        float a3 = sX[((r0 + 3) << 6) + kx];
        acc[0][0] = fmaf(a0, w.x, acc[0][0]); acc[0][1] = fmaf(a0, w.y, acc[0][1]);
        acc[0][2] = fmaf(a0, w.z, acc[0][2]); acc[0][3] = fmaf(a0, w.w, acc[0][3]);
        acc[1][0] = fmaf(a1, w.x, acc[1][0]); acc[1][1] = fmaf(a1, w.y, acc[1][1]);
        acc[1][2] = fmaf(a1, w.z, acc[1][2]); acc[1][3] = fmaf(a1, w.w, acc[1][3]);
        acc[2][0] = fmaf(a2, w.x, acc[2][0]); acc[2][1] = fmaf(a2, w.y, acc[2][1]);
        acc[2][2] = fmaf(a2, w.z, acc[2][2]); acc[2][3] = fmaf(a2, w.w, acc[2][3]);
        acc[3][0] = fmaf(a3, w.x, acc[3][0]); acc[3][1] = fmaf(a3, w.y, acc[3][1]);
        acc[3][2] = fmaf(a3, w.z, acc[3][2]); acc[3][3] = fmaf(a3, w.w, acc[3][3]);
    }
#pragma unroll 8
    for (int k = 0; k < 64; ++k) {
        const int kx = k ^ sw;
        float4 w = *(const float4*)&sW[((k + 64) << 6) + c0];
        float a0 = sA[((r0 + 0) << 6) + kx];
        float a1 = sA[((r0 + 1) << 6) + kx];
        float a2 = sA[((r0 + 2) << 6) + kx];
        float a3 = sA[((r0 + 3) << 6) + kx];
        acc[0][0] = fmaf(a0, w.x, acc[0][0]); acc[0][1] = fmaf(a0, w.y, acc[0][1]);
        acc[0][2] = fmaf(a0, w.z, acc[0][2]); acc[0][3] = fmaf(a0, w.w, acc[0][3]);
        acc[1][0] = fmaf(a1, w.x, acc[1][0]); acc[1][1] = fmaf(a1, w.y, acc[1][1]);
        acc[1][2] = fmaf(a1, w.z, acc[1][2]); acc[1][3] = fmaf(a1, w.w, acc[1][3]);
        acc[2][0] = fmaf(a2, w.x, acc[2][0]); acc[2][1] = fmaf(a2, w.y, acc[2][1]);
        acc[2][2] = fmaf(a2, w.z, acc[2][2]); acc[2][3] = fmaf(a2, w.w, acc[2][3]);
        acc[3][0] = fmaf(a3, w.x, acc[3][0]); acc[3][1] = fmaf(a3, w.y, acc[3][1]);
        acc[3][2] = fmaf(a3, w.z, acc[3][2]); acc[3][3] = fmaf(a3, w.w, acc[3][3]);
    }

#pragma unroll
    for (int i = 0; i < 4; ++i) {
        int gr = row0 + r0 + i;
        if (gr < N) {
            float4 o;
            o.x = RELU ? fmaxf(acc[i][0], 0.f) : acc[i][0];
            o.y = RELU ? fmaxf(acc[i][1], 0.f) : acc[i][1];
            o.z = RELU ? fmaxf(acc[i][2], 0.f) : acc[i][2];
            o.w = RELU ? fmaxf(acc[i][3], 0.f) : acc[i][3];
            *(float4*)(out + (size_t)gr * 64 + c0) = o;
            if (WRITE_HS) {
                float rr = rs[gr];
                float4 hsv = make_float4(o.x * rr, o.y * rr, o.z * rr, o.w * rr);
                *(float4*)(hs_out + (size_t)gr * 64 + c0) = hsv;
            }
        }
    }
}

extern "C" void kernel_launch(void* const* d_in, const int* in_sizes, int n_in,
                              void* d_out, int out_size, void* d_ws, size_t ws_size,
                              hipStream_t stream) {
    const float* x  = (const float*)d_in[0];
    const int* src  = (const int*)d_in[1];
    const int* dst  = (const int*)d_in[2];
    const float* W1 = (const float*)d_in[3];
    const float* b1 = (const float*)d_in[4];
    const float* W2 = (const float*)d_in[5];
    const float* b2 = (const float*)d_in[6];
    const float* W3 = (const float*)d_in[7];
    const float* b3 = (const float*)d_in[8];

    const int N = in_sizes[0] / 64;
    const int E = in_sizes[1];
    const int NB = (N + BMASK) >> BSHIFT;   // 1024-node buckets (NB <= 128)

    // workspace layout (~70 MB)
    float* bufH  = (float*)d_ws;                      // N*64 hidden (h1, h2)
    float* bufHS = bufH + (size_t)N * 64;             // N*64 pre-scaled features
    int* deg_out = (int*)(bufHS + (size_t)N * 64);    // N
    int* deg_in  = deg_out + N;                       // N
    float* r_out = (float*)(deg_in + N);              // N
    float* r_in  = r_out + N;                         // N
    float* r_und = r_in + N;                          // N
    int* ip_out  = (int*)(r_und + N);                 // N+1
    int* ip_in   = ip_out + (N + 1);                  // N+1
    int* bcnt_out = ip_in + (N + 1);                  // NB
    int* bcnt_in  = bcnt_out + NB;                    // NB
    int* bip_out  = bcnt_in + NB;                     // NB+1
    int* bip_in   = bip_out + (NB + 1);               // NB+1
    int* bcur_out = bip_in + (NB + 1);                // NB
    int* bcur_in  = bcur_out + NB;                    // NB
    unsigned* part_out = (unsigned*)(bcur_in + NB);   // E
    unsigned* part_in  = part_out + E;                // E
    int* col_out = (int*)(part_in + E);               // E
    int* col_in  = col_out + E;                       // E

    float* aggB = (float*)d_out;   // aggregate buffer doubles as output

    const int TPB = 256;
    const int gN  = (N + TPB - 1) / TPB;
    const int n4  = N * 16;
    const int g4  = (n4 + TPB - 1) / TPB;
    const int gAg = (int)(((size_t)N * 64 + TPB - 1) / TPB);
    const int gGm = (N + 63) / 64;
    const int gP  = (E + PCHUNK - 1) / PCHUNK;
    const int gH  = (E + HCHUNK - 1) / HCHUNK;

    // --- graph build: bucket hist -> scan -> run-reserved partition ->
    //     counting sort (emits CSR + degrees) -> r arrays ---
    hipMemsetAsync(bcnt_out, 0, 2 * (size_t)NB * sizeof(int), stream);
    bucket_hist_k<<<gH, TPB, 0, stream>>>(src, dst, bcnt_out, bcnt_in, E);
    bucket_scan_k<<<1, 1024, 0, stream>>>(bcnt_out, bcnt_in, bip_out, bip_in,
                                          bcur_out, bcur_in, NB);
    partition_k<<<gP, TPB, 0, stream>>>(src, dst, bcur_out, bcur_in,
                                        part_out, part_in, E);
    bucket_sort_k<<<dim3(NB, 2), TPB, 0, stream>>>(part_out, bip_out, part_in, bip_in,
                                                   ip_out, ip_in, col_out, col_in,
                                                   deg_out, deg_in, N, E);
    finalize_r_k<<<gN, TPB, 0, stream>>>(deg_out, deg_in, r_out, r_in, r_und, N);

    // --- layer 1: 'O' — agg over in-edges of hs0 = x * r_out ---
    scale_rows_k<<<g4, TPB, 0, stream>>>(x, r_out, bufHS, n4);
    agg_k<<<gAg, TPB, 0, stream>>>(bufHS, ip_in, col_in, aggB, N);
    gemm_cat_k<true, true><<<gGm, TPB, 0, stream>>>(x, aggB, W1, b1, r_in, bufHS, bufH, N);

    // --- layer 2: 'I' — agg over out-edges of hs1 = h1 * r_in ---
    agg_k<<<gAg, TPB, 0, stream>>>(bufHS, ip_out, col_out, aggB, N);
    gemm_cat_k<true, true><<<gGm, TPB, 0, stream>>>(bufH, aggB, W2, b2, r_und, bufHS, bufH, N);

    // --- layer 3: 'U' — agg both directions of hs2 = h2 * r_und ---
    agg_dual_k<<<gAg, TPB, 0, stream>>>(bufHS, ip_in, col_in, ip_out, col_out, aggB, N);
    gemm_cat_k<false, false><<<gGm, TPB, 0, stream>>>(bufH, aggB, W3, b3, nullptr, nullptr,
                                                      (float*)d_out, N);
}

// Round 8
// 336.658 us; speedup vs baseline: 6.1995x; 1.0864x over previous
//
#include <hip/hip_runtime.h>
#include <hip/hip_fp16.h>

// ---------------------------------------------------------------------------
// 3-layer GraphSAGE (DGL GraphConv norm='left'), N=100k, E=1M, D=H=O=64.
// Round 8: gathered features (hs) stored in FP16 (128B rows) -> halves the
// ~3.6TB/s-bound L2-miss gather traffic that dominates the profile. All
// accumulation, weights, aggregates and GEMMs remain fp32 (error ~1e-3,
// threshold 6.7e-3). Rest of the structure = round 7:
//   bucket hist -> scan -> run-reserved partition -> per-bucket counting
//   sort (emits CSR + degrees) -> per-layer {wave-per-node gather, 64x64
//   LDS-tile GEMM with next layer's fp16 pre-scale fused in the epilogue}.
// ---------------------------------------------------------------------------

#define BSHIFT 10                 // 1024-node buckets
#define BMASK  ((1 << BSHIFT) - 1)
#define NBMAX  128                // max buckets (N <= 131072)
#define PCHUNK 2048               // edges per partition block
#define HCHUNK 4096               // edges per bucket-hist block

// chunked LDS histogram of edges into buckets (both directions)
__global__ __launch_bounds__(256) void bucket_hist_k(
    const int* __restrict__ src, const int* __restrict__ dst,
    int* __restrict__ bcnt_out, int* __restrict__ bcnt_in, int E) {
    __shared__ int h0[NBMAX], h1[NBMAX];
    const int t = threadIdx.x;
    const int e0 = blockIdx.x * HCHUNK;
    int n = E - e0; if (n > HCHUNK) n = HCHUNK;
    for (int i = t; i < NBMAX; i += 256) { h0[i] = 0; h1[i] = 0; }
    __syncthreads();
    for (int i = t; i < n; i += 256) {
        atomicAdd(&h0[src[e0 + i] >> BSHIFT], 1);
        atomicAdd(&h1[dst[e0 + i] >> BSHIFT], 1);
    }
    __syncthreads();
    if (t < NBMAX) {
        int c = h0[t];
        if (c) atomicAdd(&bcnt_out[t], c);
    } else {
        int b = t - NBMAX;
        int c = h1[b];
        if (c) atomicAdd(&bcnt_in[b], c);
    }
}

// r arrays from the degree arrays emitted by bucket_sort_k
__global__ void finalize_r_k(const int* __restrict__ deg_out, const int* __restrict__ deg_in,
                             float* __restrict__ r_out, float* __restrict__ r_in,
                             float* __restrict__ r_und, int N) {
    int t = blockIdx.x * blockDim.x + threadIdx.x;
    if (t < N) {
        int a = deg_out[t], b = deg_in[t];
        r_out[t] = 1.0f / (float)(a < 1 ? 1 : a);
        r_in[t]  = 1.0f / (float)(b < 1 ? 1 : b);
        int c = a + b;
        r_und[t] = 1.0f / (float)(c < 1 ? 1 : c);
    }
}

// single-block scan of bucket counts (NB <= 1024) -> bucket prefix + cursors
__global__ void bucket_scan_k(const int* __restrict__ bcnt_out, const int* __restrict__ bcnt_in,
                              int* __restrict__ bip_out, int* __restrict__ bip_in,
                              int* __restrict__ bcur_out, int* __restrict__ bcur_in, int NB) {
    __shared__ int s[1024];
    int t = threadIdx.x;
#pragma unroll 1
    for (int pass = 0; pass < 2; ++pass) {
        const int* bcnt = pass ? bcnt_in : bcnt_out;
        int* bip = pass ? bip_in : bip_out;
        int* bcur = pass ? bcur_in : bcur_out;
        int v = (t < NB) ? bcnt[t] : 0;
        s[t] = v; __syncthreads();
        for (int off = 1; off < 1024; off <<= 1) {
            int x = (t >= off) ? s[t - off] : 0;
            __syncthreads();
            s[t] += x;
            __syncthreads();
        }
        int excl = s[t] - v;
        if (t < NB) { bip[t] = excl; bcur[t] = excl; }
        if (t == NB) bip[NB] = excl;   // == E
        __syncthreads();
    }
}

// per-block run reservation partition: one contiguous run per (block,bucket),
// so every 64B line of part_* is written by a single XCD (except run edges).
// rec = (other_node << BSHIFT) | (local_node & BMASK)
__global__ __launch_bounds__(256) void partition_k(
    const int* __restrict__ src, const int* __restrict__ dst,
    int* __restrict__ bcur_out, int* __restrict__ bcur_in,
    unsigned* __restrict__ part_out, unsigned* __restrict__ part_in, int E) {
    __shared__ int sS[PCHUNK], sD[PCHUNK];
    __shared__ int hist[2][NBMAX];    // counts, then reused as local cursors
    __shared__ int gbase[2][NBMAX];
    const int t = threadIdx.x;
    const int e0 = blockIdx.x * PCHUNK;
    int n = E - e0; if (n > PCHUNK) n = PCHUNK;

    for (int i = t; i < NBMAX; i += 256) { hist[0][i] = 0; hist[1][i] = 0; }
    __syncthreads();
    for (int i = t; i < n; i += 256) {
        int s = src[e0 + i], d = dst[e0 + i];
        sS[i] = s; sD[i] = d;
        atomicAdd(&hist[0][d >> BSHIFT], 1);   // in-partition binned by dst
        atomicAdd(&hist[1][s >> BSHIFT], 1);   // out-partition binned by src
    }
    __syncthreads();
    if (t < NBMAX) {
        int c = hist[0][t];
        gbase[0][t] = c ? atomicAdd(&bcur_in[t], c) : 0;
        hist[0][t] = 0;
    } else {
        int b = t - NBMAX;
        int c = hist[1][b];
        gbase[1][b] = c ? atomicAdd(&bcur_out[b], c) : 0;
        hist[1][b] = 0;
    }
    __syncthreads();
    for (int i = t; i < n; i += 256) {
        int s = sS[i], d = sD[i];
        int bi = d >> BSHIFT;
        int p = gbase[0][bi] + atomicAdd(&hist[0][bi], 1);
        part_in[p] = ((unsigned)s << BSHIFT) | (unsigned)(d & BMASK);
        int bo = s >> BSHIFT;
        int q = gbase[1][bo] + atomicAdd(&hist[1][bo], 1);
        part_out[q] = ((unsigned)d << BSHIFT) | (unsigned)(s & BMASK);
    }
}

// one block per (bucket, direction): counting-sort the bucket's records by
// local node id (1024 bins). Emits CSR pointers ip[], degrees deg[], col[].
__global__ __launch_bounds__(256) void bucket_sort_k(
    const unsigned* __restrict__ pa, const int* __restrict__ bipa,
    const unsigned* __restrict__ pb, const int* __restrict__ bipb,
    int* __restrict__ ipa, int* __restrict__ ipb,
    int* __restrict__ cola, int* __restrict__ colb,
    int* __restrict__ dega, int* __restrict__ degb, int N, int E) {
    const unsigned* part = blockIdx.y ? pb : pa;
    const int* bip = blockIdx.y ? bipb : bipa;
    int* ip  = blockIdx.y ? ipb : ipa;
    int* col = blockIdx.y ? colb : cola;
    int* deg = blockIdx.y ? degb : dega;
    __shared__ int cnt[1024];
    __shared__ int ps[256];
    const int g = blockIdx.x, t = threadIdx.x;
    const int b = bip[g], e = bip[g + 1];

    for (int i = t; i < 1024; i += 256) cnt[i] = 0;
    __syncthreads();
    for (int i = b + t; i < e; i += 256) atomicAdd(&cnt[part[i] & (unsigned)BMASK], 1);
    __syncthreads();

    int c0 = cnt[4 * t + 0], c1 = cnt[4 * t + 1], c2 = cnt[4 * t + 2], c3 = cnt[4 * t + 3];
    int tot = c0 + c1 + c2 + c3;
    ps[t] = tot;
    __syncthreads();
    for (int off = 1; off < 256; off <<= 1) {
        int v = (t >= off) ? ps[t - off] : 0;
        __syncthreads();
        ps[t] += v;
        __syncthreads();
    }
    int base = b + ps[t] - tot;
    int node0 = (g << BSHIFT) + 4 * t;
    int cc[4] = {c0, c1, c2, c3};
#pragma unroll
    for (int j = 0; j < 4; ++j) {
        cnt[4 * t + j] = base;           // becomes the fill cursor
        int node = node0 + j;
        if (node < N) { ip[node] = base; deg[node] = cc[j]; }
        base += cc[j];
    }
    if (g == 0 && t == 0) ip[N] = E;
    __syncthreads();
    for (int i = b + t; i < e; i += 256) {
        unsigned rec = part[i];
        int p = atomicAdd(&cnt[rec & (unsigned)BMASK], 1);
        col[p] = (int)(rec >> BSHIFT);
    }
}

// hs[row] = fp16(in[row] * r[row]); each thread converts 4 features (8B store)
__global__ void scale_rows_k(const float* __restrict__ in, const float* __restrict__ r,
                             __half* __restrict__ out, int n4) {
    int t = blockIdx.x * blockDim.x + threadIdx.x;
    if (t < n4) {
        float s = r[t >> 4];
        float4 v = ((const float4*)in)[t];
        __half2 p01 = __floats2half2_rn(v.x * s, v.y * s);
        __half2 p23 = __floats2half2_rn(v.z * s, v.w * s);
        uint2 u;
        u.x = *(unsigned*)&p01;
        u.y = *(unsigned*)&p23;
        *(uint2*)(out + ((size_t)t << 2)) = u;
    }
}

// one wave per node; 4 neighbor rows (fp16, 128B) processed concurrently,
// 16 lanes x 8B per row. Lane handles features [4fo..4fo+3], fp32 accumulate,
// cross-group shuffle reduce, quarter-wave float4 fp32 writeout.
__device__ __forceinline__ void agg_list(const __half* __restrict__ hs,
                                         const int* __restrict__ col,
                                         int b, int e, int lane, int grp, int fo,
                                         float4& acc, float4& acc2) {
    for (int base = b; base < e; base += 64) {
        int cnt = e - base; if (cnt > 64) cnt = 64;
        int my = (lane < cnt) ? col[base + lane] : 0;
        for (int j = 0; j < cnt; j += 8) {
            int i0 = j + grp, i1 = j + 4 + grp;
            int n0 = __shfl(my, i0 < cnt ? i0 : cnt - 1);
            int n1 = __shfl(my, i1 < cnt ? i1 : cnt - 1);
            uint2 u0 = *(const uint2*)(hs + ((size_t)n0 << 6) + (fo << 2));
            uint2 u1 = *(const uint2*)(hs + ((size_t)n1 << 6) + (fo << 2));
            __half2 a01 = *(__half2*)&u0.x, a23 = *(__half2*)&u0.y;
            __half2 b01 = *(__half2*)&u1.x, b23 = *(__half2*)&u1.y;
            if (i0 < cnt) {
                acc.x += __low2float(a01); acc.y += __high2float(a01);
                acc.z += __low2float(a23); acc.w += __high2float(a23);
            }
            if (i1 < cnt) {
                acc2.x += __low2float(b01); acc2.y += __high2float(b01);
                acc2.z += __low2float(b23); acc2.w += __high2float(b23);
            }
        }
    }
}

__global__ void agg_k(const __half* __restrict__ hs, const int* __restrict__ ip,
                      const int* __restrict__ col, float* __restrict__ agg, int N) {
    int node = (blockIdx.x * blockDim.x + threadIdx.x) >> 6;
    int lane = threadIdx.x & 63;
    if (node >= N) return;
    const int grp = lane >> 4, fo = lane & 15;
    float4 acc = make_float4(0.f, 0.f, 0.f, 0.f), acc2 = acc;
    agg_list(hs, col, ip[node], ip[node + 1], lane, grp, fo, acc, acc2);
    acc.x += acc2.x; acc.y += acc2.y; acc.z += acc2.z; acc.w += acc2.w;
    acc.x += __shfl_xor(acc.x, 16); acc.y += __shfl_xor(acc.y, 16);
    acc.z += __shfl_xor(acc.z, 16); acc.w += __shfl_xor(acc.w, 16);
    acc.x += __shfl_xor(acc.x, 32); acc.y += __shfl_xor(acc.y, 32);
    acc.z += __shfl_xor(acc.z, 32); acc.w += __shfl_xor(acc.w, 32);
    if (lane < 16) ((float4*)(agg + ((size_t)node << 6)))[fo] = acc;
}

__global__ void agg_dual_k(const __half* __restrict__ hs,
                           const int* __restrict__ ipA, const int* __restrict__ colA,
                           const int* __restrict__ ipB, const int* __restrict__ colB,
                           float* __restrict__ agg, int N) {
    int node = (blockIdx.x * blockDim.x + threadIdx.x) >> 6;
    int lane = threadIdx.x & 63;
    if (node >= N) return;
    const int grp = lane >> 4, fo = lane & 15;
    float4 acc = make_float4(0.f, 0.f, 0.f, 0.f), acc2 = acc;
    agg_list(hs, colA, ipA[node], ipA[node + 1], lane, grp, fo, acc, acc2);
    agg_list(hs, colB, ipB[node], ipB[node + 1], lane, grp, fo, acc, acc2);
    acc.x += acc2.x; acc.y += acc2.y; acc.z += acc2.z; acc.w += acc2.w;
    acc.x += __shfl_xor(acc.x, 16); acc.y += __shfl_xor(acc.y, 16);
    acc.z += __shfl_xor(acc.z, 16); acc.w += __shfl_xor(acc.w, 16);
    acc.x += __shfl_xor(acc.x, 32); acc.y += __shfl_xor(acc.y, 32);
    acc.z += __shfl_xor(acc.z, 32); acc.w += __shfl_xor(acc.w, 32);
    if (lane < 16) ((float4*)(agg + ((size_t)node << 6)))[fo] = acc;
}

// out = [X, A] @ W + B (optional relu); optionally hs_out = fp16(out * rs[row])
// fused in the epilogue (pre-scaled fp16 features for the next layer's gather).
// 256 threads -> 64x64 tile, 4x4 per-thread, fp32. LDS 64KB. XOR-swizzled.
template <bool RELU, bool WRITE_HS>
__global__ __launch_bounds__(256, 2) void gemm_cat_k(
    const float* X, const float* A,
    const float* __restrict__ W, const float* __restrict__ B,
    const float* __restrict__ rs, __half* __restrict__ hs_out,
    float* out, int N) {
    __shared__ float sW[128 * 64];
    __shared__ float sX[64 * 64];
    __shared__ float sA[64 * 64];
    const int tid = threadIdx.x;

    for (int i = tid; i < 2048; i += 256) ((float4*)sW)[i] = ((const float4*)W)[i];

    const int row0 = blockIdx.x * 64;
    for (int i = tid; i < 1024; i += 256) {
        int r = i >> 4, c4 = (i & 15) << 2;
        int gr = row0 + r;
        float4 xv = make_float4(0.f, 0.f, 0.f, 0.f), av = xv;
        if (gr < N) {
            xv = ((const float4*)X)[(size_t)gr * 16 + (i & 15)];
            av = ((const float4*)A)[(size_t)gr * 16 + (i & 15)];
        }
        int sc = c4 ^ ((r & 12) << 1);
        *(float4*)&sX[(r << 6) + sc] = xv;
        *(float4*)&sA[(r << 6) + sc] = av;
    }
    __syncthreads();

    const int c0 = (tid & 15) << 2;
    const int r0 = (tid >> 4) << 2;
    const int sw = (r0 & 12) << 1;

    float4 bv = *(const float4*)(B + c0);
    float acc[4][4];
#pragma unroll
    for (int i = 0; i < 4; ++i) {
        acc[i][0] = bv.x; acc[i][1] = bv.y; acc[i][2] = bv.z; acc[i][3] = bv.w;
    }

#pragma unroll 8
    for (int k = 0; k < 64; ++k) {
        const int kx = k ^ sw;
        float4 w = *(const float4*)&sW[(k << 6) + c0];
        float a0 = sX[((r0 + 0) << 6) + kx];
        float a1 = sX[((r0 + 1) << 6) + kx];
        float a2 = sX[((r0 + 2) << 6) + kx];
        float a3 = sX[((r0 + 3) << 6) + kx];
        acc[0][0] = fmaf(a0, w.x, acc[0][0]); acc[0][1] = fmaf(a0, w.y, acc[0][1]);
        acc[0][2] = fmaf(a0, w.z, acc[0][2]); acc[0][3] = fmaf(a0, w.w, acc[0][3]);
        acc[1][0] = fmaf(a1, w.x, acc[1][0]); acc[1][1] = fmaf(a1, w.y, acc[1][1]);
        acc[1][2] = fmaf(a1, w.z, acc[1][2]); acc[1][3] = fmaf(a1, w.w, acc[1][3]);
        acc[2][0] = fmaf(a2, w.x, acc[2][0]); acc[2][1] = fmaf(a2, w.y, acc[2][1]);
        acc[2][2] = fmaf(a2, w.z, acc[2][2]); acc[2][3] = fmaf(a2, w.w, acc[2][3]);
        acc[3][0] = fmaf(a3, w.x, acc[3][0]); acc[3][1] = fmaf(a3, w.y, acc[3][1]);
        acc[3][2] = fmaf(a3, w.z, acc[3][2]); acc[3][3] = fmaf(a3, w.w, acc[3][3]);
    }
#pragma unroll 8
    for (int k = 0; k < 64; ++k) {
        const int kx = k ^ sw;
        float4 w = *(const float4*)&sW[((k + 64) << 6) + c0];
        float a0 = sA[((r0 + 0) << 6) + kx];
        float a1 = sA[((r0 + 1) << 6) + kx];
        float a2 = sA[((r0 + 2) << 6) + kx];
        float a3 = sA[((r0 + 3) << 6) + kx];
        acc[0][0] = fmaf(a0, w.x, acc[0][0]); acc[0][1] = fmaf(a0, w.y, acc[0][1]);
        acc[0][2] = fmaf(a0, w.z, acc[0][2]); acc[0][3] = fmaf(a0, w.w, acc[0][3]);
        acc[1][0] = fmaf(a1, w.x, acc[1][0]); acc[1][1] = fmaf(a1, w.y, acc[1][1]);
        acc[1][2] = fmaf(a1, w.z, acc[1][2]); acc[1][3] = fmaf(a1, w.w, acc[1][3]);
        acc[2][0] = fmaf(a2, w.x, acc[2][0]); acc[2][1] = fmaf(a2, w.y, acc[2][1]);
        acc[2][2] = fmaf(a2, w.z, acc[2][2]); acc[2][3] = fmaf(a2, w.w, acc[2][3]);
        acc[3][0] = fmaf(a3, w.x, acc[3][0]); acc[3][1] = fmaf(a3, w.y, acc[3][1]);
        acc[3][2] = fmaf(a3, w.z, acc[3][2]); acc[3][3] = fmaf(a3, w.w, acc[3][3]);
    }

#pragma unroll
    for (int i = 0; i < 4; ++i) {
        int gr = row0 + r0 + i;
        if (gr < N) {
            float4 o;
            o.x = RELU ? fmaxf(acc[i][0], 0.f) : acc[i][0];
            o.y = RELU ? fmaxf(acc[i][1], 0.f) : acc[i][1];
            o.z = RELU ? fmaxf(acc[i][2], 0.f) : acc[i][2];
            o.w = RELU ? fmaxf(acc[i][3], 0.f) : acc[i][3];
            *(float4*)(out + ((size_t)gr << 6) + c0) = o;
            if (WRITE_HS) {
                float rr = rs[gr];
                __half2 p01 = __floats2half2_rn(o.x * rr, o.y * rr);
                __half2 p23 = __floats2half2_rn(o.z * rr, o.w * rr);
                uint2 u;
                u.x = *(unsigned*)&p01;
                u.y = *(unsigned*)&p23;
                *(uint2*)(hs_out + ((size_t)gr << 6) + c0) = u;
            }
        }
    }
}

extern "C" void kernel_launch(void* const* d_in, const int* in_sizes, int n_in,
                              void* d_out, int out_size, void* d_ws, size_t ws_size,
                              hipStream_t stream) {
    const float* x  = (const float*)d_in[0];
    const int* src  = (const int*)d_in[1];
    const int* dst  = (const int*)d_in[2];
    const float* W1 = (const float*)d_in[3];
    const float* b1 = (const float*)d_in[4];
    const float* W2 = (const float*)d_in[5];
    const float* b2 = (const float*)d_in[6];
    const float* W3 = (const float*)d_in[7];
    const float* b3 = (const float*)d_in[8];

    const int N = in_sizes[0] / 64;
    const int E = in_sizes[1];
    const int NB = (N + BMASK) >> BSHIFT;   // 1024-node buckets (NB <= 128)

    // workspace layout
    float* bufH  = (float*)d_ws;                      // N*64 f32 hidden (h1, h2)
    __half* bufHS = (__half*)(bufH + (size_t)N * 64); // N*64 fp16 pre-scaled feats
    int* deg_out = (int*)(bufHS + (size_t)N * 64);    // N
    int* deg_in  = deg_out + N;                       // N
    float* r_out = (float*)(deg_in + N);              // N
    float* r_in  = r_out + N;                         // N
    float* r_und = r_in + N;                          // N
    int* ip_out  = (int*)(r_und + N);                 // N+1
    int* ip_in   = ip_out + (N + 1);                  // N+1
    int* bcnt_out = ip_in + (N + 1);                  // NB
    int* bcnt_in  = bcnt_out + NB;                    // NB
    int* bip_out  = bcnt_in + NB;                     // NB+1
    int* bip_in   = bip_out + (NB + 1);               // NB+1
    int* bcur_out = bip_in + (NB + 1);                // NB
    int* bcur_in  = bcur_out + NB;                    // NB
    unsigned* part_out = (unsigned*)(bcur_in + NB);   // E
    unsigned* part_in  = part_out + E;                // E
    int* col_out = (int*)(part_in + E);               // E
    int* col_in  = col_out + E;                       // E

    float* aggB = (float*)d_out;   // aggregate buffer doubles as output

    const int TPB = 256;
    const int gN  = (N + TPB - 1) / TPB;
    const int n4  = N * 16;
    const int g4  = (n4 + TPB - 1) / TPB;
    const int gAg = (int)(((size_t)N * 64 + TPB - 1) / TPB);
    const int gGm = (N + 63) / 64;
    const int gP  = (E + PCHUNK - 1) / PCHUNK;
    const int gH  = (E + HCHUNK - 1) / HCHUNK;

    // --- graph build: bucket hist -> scan -> run-reserved partition ->
    //     counting sort (emits CSR + degrees) -> r arrays ---
    hipMemsetAsync(bcnt_out, 0, 2 * (size_t)NB * sizeof(int), stream);
    bucket_hist_k<<<gH, TPB, 0, stream>>>(src, dst, bcnt_out, bcnt_in, E);
    bucket_scan_k<<<1, 1024, 0, stream>>>(bcnt_out, bcnt_in, bip_out, bip_in,
                                          bcur_out, bcur_in, NB);
    partition_k<<<gP, TPB, 0, stream>>>(src, dst, bcur_out, bcur_in,
                                        part_out, part_in, E);
    bucket_sort_k<<<dim3(NB, 2), TPB, 0, stream>>>(part_out, bip_out, part_in, bip_in,
                                                   ip_out, ip_in, col_out, col_in,
                                                   deg_out, deg_in, N, E);
    finalize_r_k<<<gN, TPB, 0, stream>>>(deg_out, deg_in, r_out, r_in, r_und, N);

    // --- layer 1: 'O' — agg over in-edges of hs0 = fp16(x * r_out) ---
    scale_rows_k<<<g4, TPB, 0, stream>>>(x, r_out, bufHS, n4);
    agg_k<<<gAg, TPB, 0, stream>>>(bufHS, ip_in, col_in, aggB, N);
    gemm_cat_k<true, true><<<gGm, TPB, 0, stream>>>(x, aggB, W1, b1, r_in, bufHS, bufH, N);

    // --- layer 2: 'I' — agg over out-edges of hs1 = fp16(h1 * r_in) ---
    agg_k<<<gAg, TPB, 0, stream>>>(bufHS, ip_out, col_out, aggB, N);
    gemm_cat_k<true, true><<<gGm, TPB, 0, stream>>>(bufH, aggB, W2, b2, r_und, bufHS, bufH, N);

    // --- layer 3: 'U' — agg both directions of hs2 = fp16(h2 * r_und) ---
    agg_dual_k<<<gAg, TPB, 0, stream>>>(bufHS, ip_in, col_in, ip_out, col_out, aggB, N);
    gemm_cat_k<false, false><<<gGm, TPB, 0, stream>>>(bufH, aggB, W3, b3, nullptr, nullptr,
                                                      (float*)d_out, N);
}

// Round 9
// 304.437 us; speedup vs baseline: 6.8557x; 1.1058x over previous
//
#include <hip/hip_runtime.h>
#include <hip/hip_fp16.h>

// ---------------------------------------------------------------------------
// 3-layer GraphSAGE (DGL GraphConv norm='left'), N=100k, E=1M, D=H=O=64.
// Round 9 (structure = round 8):
//  * agg gather MLP depth 2 -> 4: 16 edges per inner iter, 4 independent
//    fp16-row loads in flight per lane, 4 fp32 accumulator chains (gather is
//    L2-hit latency-bound: FETCH 103MB = 8 XCDs x 12.8MB hs, one-time).
//  * GEMM k-blocked x4: A-row read as float4 (swizzle is 8-granular so
//    (kb^sw)+j stays contiguous for j<4) + 4 W-rows/step -> 8 b128 LDS reads
//    per 64 fma (DS ~96cy < VALU 128cy) instead of 4 b128 + 16 b32 (~141cy).
// ---------------------------------------------------------------------------

#define BSHIFT 10                 // 1024-node buckets
#define BMASK  ((1 << BSHIFT) - 1)
#define NBMAX  128                // max buckets (N <= 131072)
#define PCHUNK 2048               // edges per partition block
#define HCHUNK 4096               // edges per bucket-hist block

// chunked LDS histogram of edges into buckets (both directions)
__global__ __launch_bounds__(256) void bucket_hist_k(
    const int* __restrict__ src, const int* __restrict__ dst,
    int* __restrict__ bcnt_out, int* __restrict__ bcnt_in, int E) {
    __shared__ int h0[NBMAX], h1[NBMAX];
    const int t = threadIdx.x;
    const int e0 = blockIdx.x * HCHUNK;
    int n = E - e0; if (n > HCHUNK) n = HCHUNK;
    for (int i = t; i < NBMAX; i += 256) { h0[i] = 0; h1[i] = 0; }
    __syncthreads();
    for (int i = t; i < n; i += 256) {
        atomicAdd(&h0[src[e0 + i] >> BSHIFT], 1);
        atomicAdd(&h1[dst[e0 + i] >> BSHIFT], 1);
    }
    __syncthreads();
    if (t < NBMAX) {
        int c = h0[t];
        if (c) atomicAdd(&bcnt_out[t], c);
    } else {
        int b = t - NBMAX;
        int c = h1[b];
        if (c) atomicAdd(&bcnt_in[b], c);
    }
}

// r arrays from the degree arrays emitted by bucket_sort_k
__global__ void finalize_r_k(const int* __restrict__ deg_out, const int* __restrict__ deg_in,
                             float* __restrict__ r_out, float* __restrict__ r_in,
                             float* __restrict__ r_und, int N) {
    int t = blockIdx.x * blockDim.x + threadIdx.x;
    if (t < N) {
        int a = deg_out[t], b = deg_in[t];
        r_out[t] = 1.0f / (float)(a < 1 ? 1 : a);
        r_in[t]  = 1.0f / (float)(b < 1 ? 1 : b);
        int c = a + b;
        r_und[t] = 1.0f / (float)(c < 1 ? 1 : c);
    }
}

// single-block scan of bucket counts (NB <= 1024) -> bucket prefix + cursors
__global__ void bucket_scan_k(const int* __restrict__ bcnt_out, const int* __restrict__ bcnt_in,
                              int* __restrict__ bip_out, int* __restrict__ bip_in,
                              int* __restrict__ bcur_out, int* __restrict__ bcur_in, int NB) {
    __shared__ int s[1024];
    int t = threadIdx.x;
#pragma unroll 1
    for (int pass = 0; pass < 2; ++pass) {
        const int* bcnt = pass ? bcnt_in : bcnt_out;
        int* bip = pass ? bip_in : bip_out;
        int* bcur = pass ? bcur_in : bcur_out;
        int v = (t < NB) ? bcnt[t] : 0;
        s[t] = v; __syncthreads();
        for (int off = 1; off < 1024; off <<= 1) {
            int x = (t >= off) ? s[t - off] : 0;
            __syncthreads();
            s[t] += x;
            __syncthreads();
        }
        int excl = s[t] - v;
        if (t < NB) { bip[t] = excl; bcur[t] = excl; }
        if (t == NB) bip[NB] = excl;   // == E
        __syncthreads();
    }
}

// per-block run reservation partition: one contiguous run per (block,bucket),
// so every 64B line of part_* is written by a single XCD (except run edges).
// rec = (other_node << BSHIFT) | (local_node & BMASK)
__global__ __launch_bounds__(256) void partition_k(
    const int* __restrict__ src, const int* __restrict__ dst,
    int* __restrict__ bcur_out, int* __restrict__ bcur_in,
    unsigned* __restrict__ part_out, unsigned* __restrict__ part_in, int E) {
    __shared__ int sS[PCHUNK], sD[PCHUNK];
    __shared__ int hist[2][NBMAX];    // counts, then reused as local cursors
    __shared__ int gbase[2][NBMAX];
    const int t = threadIdx.x;
    const int e0 = blockIdx.x * PCHUNK;
    int n = E - e0; if (n > PCHUNK) n = PCHUNK;

    for (int i = t; i < NBMAX; i += 256) { hist[0][i] = 0; hist[1][i] = 0; }
    __syncthreads();
    for (int i = t; i < n; i += 256) {
        int s = src[e0 + i], d = dst[e0 + i];
        sS[i] = s; sD[i] = d;
        atomicAdd(&hist[0][d >> BSHIFT], 1);   // in-partition binned by dst
        atomicAdd(&hist[1][s >> BSHIFT], 1);   // out-partition binned by src
    }
    __syncthreads();
    if (t < NBMAX) {
        int c = hist[0][t];
        gbase[0][t] = c ? atomicAdd(&bcur_in[t], c) : 0;
        hist[0][t] = 0;
    } else {
        int b = t - NBMAX;
        int c = hist[1][b];
        gbase[1][b] = c ? atomicAdd(&bcur_out[b], c) : 0;
        hist[1][b] = 0;
    }
    __syncthreads();
    for (int i = t; i < n; i += 256) {
        int s = sS[i], d = sD[i];
        int bi = d >> BSHIFT;
        int p = gbase[0][bi] + atomicAdd(&hist[0][bi], 1);
        part_in[p] = ((unsigned)s << BSHIFT) | (unsigned)(d & BMASK);
        int bo = s >> BSHIFT;
        int q = gbase[1][bo] + atomicAdd(&hist[1][bo], 1);
        part_out[q] = ((unsigned)d << BSHIFT) | (unsigned)(s & BMASK);
    }
}

// one block per (bucket, direction): counting-sort the bucket's records by
// local node id (1024 bins). Emits CSR pointers ip[], degrees deg[], col[].
__global__ __launch_bounds__(256) void bucket_sort_k(
    const unsigned* __restrict__ pa, const int* __restrict__ bipa,
    const unsigned* __restrict__ pb, const int* __restrict__ bipb,
    int* __restrict__ ipa, int* __restrict__ ipb,
    int* __restrict__ cola, int* __restrict__ colb,
    int* __restrict__ dega, int* __restrict__ degb, int N, int E) {
    const unsigned* part = blockIdx.y ? pb : pa;
    const int* bip = blockIdx.y ? bipb : bipa;
    int* ip  = blockIdx.y ? ipb : ipa;
    int* col = blockIdx.y ? colb : cola;
    int* deg = blockIdx.y ? degb : dega;
    __shared__ int cnt[1024];
    __shared__ int ps[256];
    const int g = blockIdx.x, t = threadIdx.x;
    const int b = bip[g], e = bip[g + 1];

    for (int i = t; i < 1024; i += 256) cnt[i] = 0;
    __syncthreads();
    for (int i = b + t; i < e; i += 256) atomicAdd(&cnt[part[i] & (unsigned)BMASK], 1);
    __syncthreads();

    int c0 = cnt[4 * t + 0], c1 = cnt[4 * t + 1], c2 = cnt[4 * t + 2], c3 = cnt[4 * t + 3];
    int tot = c0 + c1 + c2 + c3;
    ps[t] = tot;
    __syncthreads();
    for (int off = 1; off < 256; off <<= 1) {
        int v = (t >= off) ? ps[t - off] : 0;
        __syncthreads();
        ps[t] += v;
        __syncthreads();
    }
    int base = b + ps[t] - tot;
    int node0 = (g << BSHIFT) + 4 * t;
    int cc[4] = {c0, c1, c2, c3};
#pragma unroll
    for (int j = 0; j < 4; ++j) {
        cnt[4 * t + j] = base;           // becomes the fill cursor
        int node = node0 + j;
        if (node < N) { ip[node] = base; deg[node] = cc[j]; }
        base += cc[j];
    }
    if (g == 0 && t == 0) ip[N] = E;
    __syncthreads();
    for (int i = b + t; i < e; i += 256) {
        unsigned rec = part[i];
        int p = atomicAdd(&cnt[rec & (unsigned)BMASK], 1);
        col[p] = (int)(rec >> BSHIFT);
    }
}

// hs[row] = fp16(in[row] * r[row]); each thread converts 4 features (8B store)
__global__ void scale_rows_k(const float* __restrict__ in, const float* __restrict__ r,
                             __half* __restrict__ out, int n4) {
    int t = blockIdx.x * blockDim.x + threadIdx.x;
    if (t < n4) {
        float s = r[t >> 4];
        float4 v = ((const float4*)in)[t];
        __half2 p01 = __floats2half2_rn(v.x * s, v.y * s);
        __half2 p23 = __floats2half2_rn(v.z * s, v.w * s);
        uint2 u;
        u.x = *(unsigned*)&p01;
        u.y = *(unsigned*)&p23;
        *(uint2*)(out + ((size_t)t << 2)) = u;
    }
}

// one wave per node; 16 edges per inner iter, 4 fp16 rows (128B each) in
// flight per lane (16 lanes x 8B per row), 4 independent fp32 acc chains.
__device__ __forceinline__ void acc_row(float4& acc, uint2 u) {
    __half2 h01 = *(__half2*)&u.x, h23 = *(__half2*)&u.y;
    acc.x += __low2float(h01); acc.y += __high2float(h01);
    acc.z += __low2float(h23); acc.w += __high2float(h23);
}

__device__ __forceinline__ void agg_list(const __half* __restrict__ hs,
                                         const int* __restrict__ col,
                                         int b, int e, int lane, int grp, int fo,
                                         float4& a0, float4& a1, float4& a2, float4& a3) {
    for (int base = b; base < e; base += 64) {
        int cnt = e - base; if (cnt > 64) cnt = 64;
        int my = (lane < cnt) ? col[base + lane] : 0;
        for (int j = 0; j < cnt; j += 16) {
            int i0 = j + grp, i1 = j + 4 + grp, i2 = j + 8 + grp, i3 = j + 12 + grp;
            int n0 = __shfl(my, i0 < cnt ? i0 : 0);
            int n1 = __shfl(my, i1 < cnt ? i1 : 0);
            int n2 = __shfl(my, i2 < cnt ? i2 : 0);
            int n3 = __shfl(my, i3 < cnt ? i3 : 0);
            uint2 u0 = *(const uint2*)(hs + ((size_t)n0 << 6) + (fo << 2));
            uint2 u1 = *(const uint2*)(hs + ((size_t)n1 << 6) + (fo << 2));
            uint2 u2 = *(const uint2*)(hs + ((size_t)n2 << 6) + (fo << 2));
            uint2 u3 = *(const uint2*)(hs + ((size_t)n3 << 6) + (fo << 2));
            if (i0 < cnt) acc_row(a0, u0);
            if (i1 < cnt) acc_row(a1, u1);
            if (i2 < cnt) acc_row(a2, u2);
            if (i3 < cnt) acc_row(a3, u3);
        }
    }
}

__device__ __forceinline__ void agg_finish(float4 a0, float4 a1, float4 a2, float4 a3,
                                           float* __restrict__ agg, int node,
                                           int lane, int fo) {
    float4 acc;
    acc.x = (a0.x + a1.x) + (a2.x + a3.x);
    acc.y = (a0.y + a1.y) + (a2.y + a3.y);
    acc.z = (a0.z + a1.z) + (a2.z + a3.z);
    acc.w = (a0.w + a1.w) + (a2.w + a3.w);
    acc.x += __shfl_xor(acc.x, 16); acc.y += __shfl_xor(acc.y, 16);
    acc.z += __shfl_xor(acc.z, 16); acc.w += __shfl_xor(acc.w, 16);
    acc.x += __shfl_xor(acc.x, 32); acc.y += __shfl_xor(acc.y, 32);
    acc.z += __shfl_xor(acc.z, 32); acc.w += __shfl_xor(acc.w, 32);
    if (lane < 16) ((float4*)(agg + ((size_t)node << 6)))[fo] = acc;
}

__global__ void agg_k(const __half* __restrict__ hs, const int* __restrict__ ip,
                      const int* __restrict__ col, float* __restrict__ agg, int N) {
    int node = (blockIdx.x * blockDim.x + threadIdx.x) >> 6;
    int lane = threadIdx.x & 63;
    if (node >= N) return;
    const int grp = lane >> 4, fo = lane & 15;
    float4 z = make_float4(0.f, 0.f, 0.f, 0.f);
    float4 a0 = z, a1 = z, a2 = z, a3 = z;
    agg_list(hs, col, ip[node], ip[node + 1], lane, grp, fo, a0, a1, a2, a3);
    agg_finish(a0, a1, a2, a3, agg, node, lane, fo);
}

__global__ void agg_dual_k(const __half* __restrict__ hs,
                           const int* __restrict__ ipA, const int* __restrict__ colA,
                           const int* __restrict__ ipB, const int* __restrict__ colB,
                           float* __restrict__ agg, int N) {
    int node = (blockIdx.x * blockDim.x + threadIdx.x) >> 6;
    int lane = threadIdx.x & 63;
    if (node >= N) return;
    const int grp = lane >> 4, fo = lane & 15;
    float4 z = make_float4(0.f, 0.f, 0.f, 0.f);
    float4 a0 = z, a1 = z, a2 = z, a3 = z;
    agg_list(hs, colA, ipA[node], ipA[node + 1], lane, grp, fo, a0, a1, a2, a3);
    agg_list(hs, colB, ipB[node], ipB[node + 1], lane, grp, fo, a0, a1, a2, a3);
    agg_finish(a0, a1, a2, a3, agg, node, lane, fo);
}

// out = [X, A] @ W + B (optional relu); optionally hs_out = fp16(out * rs[row])
// fused in the epilogue. 256 threads -> 64x64 tile, 4x4 per-thread, fp32.
// k-blocked x4: A-rows read as float4 (swizzle XOR is 8-granular so low 2 bits
// pass through), 4 W-rows per step -> 8 b128 LDS reads per 64 fma.
template <bool RELU, bool WRITE_HS>
__global__ __launch_bounds__(256, 2) void gemm_cat_k(
    const float* X, const float* A,
    const float* __restrict__ W, const float* __restrict__ B,
    const float* __restrict__ rs, __half* __restrict__ hs_out,
    float* out, int N) {
    __shared__ float sW[128 * 64];
    __shared__ float sX[64 * 64];
    __shared__ float sA[64 * 64];
    const int tid = threadIdx.x;

    for (int i = tid; i < 2048; i += 256) ((float4*)sW)[i] = ((const float4*)W)[i];

    const int row0 = blockIdx.x * 64;
    for (int i = tid; i < 1024; i += 256) {
        int r = i >> 4, c4 = (i & 15) << 2;
        int gr = row0 + r;
        float4 xv = make_float4(0.f, 0.f, 0.f, 0.f), av = xv;
        if (gr < N) {
            xv = ((const float4*)X)[(size_t)gr * 16 + (i & 15)];
            av = ((const float4*)A)[(size_t)gr * 16 + (i & 15)];
        }
        int sc = c4 ^ ((r & 12) << 1);
        *(float4*)&sX[(r << 6) + sc] = xv;
        *(float4*)&sA[(r << 6) + sc] = av;
    }
    __syncthreads();

    const int c0 = (tid & 15) << 2;
    const int r0 = (tid >> 4) << 2;
    const int sw = (r0 & 12) << 1;

    float4 bv = *(const float4*)(B + c0);
    float acc[4][4];
#pragma unroll
    for (int i = 0; i < 4; ++i) {
        acc[i][0] = bv.x; acc[i][1] = bv.y; acc[i][2] = bv.z; acc[i][3] = bv.w;
    }

#define GEMM_ROW(i, av)                                                       \
    acc[i][0] = fmaf(av.x, w0.x, acc[i][0]); acc[i][1] = fmaf(av.x, w0.y, acc[i][1]); \
    acc[i][2] = fmaf(av.x, w0.z, acc[i][2]); acc[i][3] = fmaf(av.x, w0.w, acc[i][3]); \
    acc[i][0] = fmaf(av.y, w1.x, acc[i][0]); acc[i][1] = fmaf(av.y, w1.y, acc[i][1]); \
    acc[i][2] = fmaf(av.y, w1.z, acc[i][2]); acc[i][3] = fmaf(av.y, w1.w, acc[i][3]); \
    acc[i][0] = fmaf(av.z, w2.x, acc[i][0]); acc[i][1] = fmaf(av.z, w2.y, acc[i][1]); \
    acc[i][2] = fmaf(av.z, w2.z, acc[i][2]); acc[i][3] = fmaf(av.z, w2.w, acc[i][3]); \
    acc[i][0] = fmaf(av.w, w3.x, acc[i][0]); acc[i][1] = fmaf(av.w, w3.y, acc[i][1]); \
    acc[i][2] = fmaf(av.w, w3.z, acc[i][2]); acc[i][3] = fmaf(av.w, w3.w, acc[i][3]);

#pragma unroll 4
    for (int kb = 0; kb < 64; kb += 4) {
        const int kx = kb ^ sw;
        float4 w0 = *(const float4*)&sW[((kb + 0) << 6) + c0];
        float4 w1 = *(const float4*)&sW[((kb + 1) << 6) + c0];
        float4 w2 = *(const float4*)&sW[((kb + 2) << 6) + c0];
        float4 w3 = *(const float4*)&sW[((kb + 3) << 6) + c0];
        float4 a0 = *(const float4*)&sX[((r0 + 0) << 6) + kx];
        float4 a1 = *(const float4*)&sX[((r0 + 1) << 6) + kx];
        float4 a2 = *(const float4*)&sX[((r0 + 2) << 6) + kx];
        float4 a3 = *(const float4*)&sX[((r0 + 3) << 6) + kx];
        GEMM_ROW(0, a0) GEMM_ROW(1, a1) GEMM_ROW(2, a2) GEMM_ROW(3, a3)
    }
#pragma unroll 4
    for (int kb = 0; kb < 64; kb += 4) {
        const int kx = kb ^ sw;
        float4 w0 = *(const float4*)&sW[((kb + 64) << 6) + c0];
        float4 w1 = *(const float4*)&sW[((kb + 65) << 6) + c0];
        float4 w2 = *(const float4*)&sW[((kb + 66) << 6) + c0];
        float4 w3 = *(const float4*)&sW[((kb + 67) << 6) + c0];
        float4 a0 = *(const float4*)&sA[((r0 + 0) << 6) + kx];
        float4 a1 = *(const float4*)&sA[((r0 + 1) << 6) + kx];
        float4 a2 = *(const float4*)&sA[((r0 + 2) << 6) + kx];
        float4 a3 = *(const float4*)&sA[((r0 + 3) << 6) + kx];
        GEMM_ROW(0, a0) GEMM_ROW(1, a1) GEMM_ROW(2, a2) GEMM_ROW(3, a3)
    }
#undef GEMM_ROW

#pragma unroll
    for (int i = 0; i < 4; ++i) {
        int gr = row0 + r0 + i;
        if (gr < N) {
            float4 o;
            o.x = RELU ? fmaxf(acc[i][0], 0.f) : acc[i][0];
            o.y = RELU ? fmaxf(acc[i][1], 0.f) : acc[i][1];
            o.z = RELU ? fmaxf(acc[i][2], 0.f) : acc[i][2];
            o.w = RELU ? fmaxf(acc[i][3], 0.f) : acc[i][3];
            *(float4*)(out + ((size_t)gr << 6) + c0) = o;
            if (WRITE_HS) {
                float rr = rs[gr];
                __half2 p01 = __floats2half2_rn(o.x * rr, o.y * rr);
                __half2 p23 = __floats2half2_rn(o.z * rr, o.w * rr);
                uint2 u;
                u.x = *(unsigned*)&p01;
                u.y = *(unsigned*)&p23;
                *(uint2*)(hs_out + ((size_t)gr << 6) + c0) = u;
            }
        }
    }
}

extern "C" void kernel_launch(void* const* d_in, const int* in_sizes, int n_in,
                              void* d_out, int out_size, void* d_ws, size_t ws_size,
                              hipStream_t stream) {
    const float* x  = (const float*)d_in[0];
    const int* src  = (const int*)d_in[1];
    const int* dst  = (const int*)d_in[2];
    const float* W1 = (const float*)d_in[3];
    const float* b1 = (const float*)d_in[4];
    const float* W2 = (const float*)d_in[5];
    const float* b2 = (const float*)d_in[6];
    const float* W3 = (const float*)d_in[7];
    const float* b3 = (const float*)d_in[8];

    const int N = in_sizes[0] / 64;
    const int E = in_sizes[1];
    const int NB = (N + BMASK) >> BSHIFT;   // 1024-node buckets (NB <= 128)

    // workspace layout
    float* bufH  = (float*)d_ws;                      // N*64 f32 hidden (h1, h2)
    __half* bufHS = (__half*)(bufH + (size_t)N * 64); // N*64 fp16 pre-scaled feats
    int* deg_out = (int*)(bufHS + (size_t)N * 64);    // N
    int* deg_in  = deg_out + N;                       // N
    float* r_out = (float*)(deg_in + N);              // N
    float* r_in  = r_out + N;                         // N
    float* r_und = r_in + N;                          // N
    int* ip_out  = (int*)(r_und + N);                 // N+1
    int* ip_in   = ip_out + (N + 1);                  // N+1
    int* bcnt_out = ip_in + (N + 1);                  // NB
    int* bcnt_in  = bcnt_out + NB;                    // NB
    int* bip_out  = bcnt_in + NB;                     // NB+1
    int* bip_in   = bip_out + (NB + 1);               // NB+1
    int* bcur_out = bip_in + (NB + 1);                // NB
    int* bcur_in  = bcur_out + NB;                    // NB
    unsigned* part_out = (unsigned*)(bcur_in + NB);   // E
    unsigned* part_in  = part_out + E;                // E
    int* col_out = (int*)(part_in + E);               // E
    int* col_in  = col_out + E;                       // E

    float* aggB = (float*)d_out;   // aggregate buffer doubles as output

    const int TPB = 256;
    const int gN  = (N + TPB - 1) / TPB;
    const int n4  = N * 16;
    const int g4  = (n4 + TPB - 1) / TPB;
    const int gAg = (int)(((size_t)N * 64 + TPB - 1) / TPB);
    const int gGm = (N + 63) / 64;
    const int gP  = (E + PCHUNK - 1) / PCHUNK;
    const int gH  = (E + HCHUNK - 1) / HCHUNK;

    // --- graph build: bucket hist -> scan -> run-reserved partition ->
    //     counting sort (emits CSR + degrees) -> r arrays ---
    hipMemsetAsync(bcnt_out, 0, 2 * (size_t)NB * sizeof(int), stream);
    bucket_hist_k<<<gH, TPB, 0, stream>>>(src, dst, bcnt_out, bcnt_in, E);
    bucket_scan_k<<<1, 1024, 0, stream>>>(bcnt_out, bcnt_in, bip_out, bip_in,
                                          bcur_out, bcur_in, NB);
    partition_k<<<gP, TPB, 0, stream>>>(src, dst, bcur_out, bcur_in,
                                        part_out, part_in, E);
    bucket_sort_k<<<dim3(NB, 2), TPB, 0, stream>>>(part_out, bip_out, part_in, bip_in,
                                                   ip_out, ip_in, col_out, col_in,
                                                   deg_out, deg_in, N, E);
    finalize_r_k<<<gN, TPB, 0, stream>>>(deg_out, deg_in, r_out, r_in, r_und, N);

    // --- layer 1: 'O' — agg over in-edges of hs0 = fp16(x * r_out) ---
    scale_rows_k<<<g4, TPB, 0, stream>>>(x, r_out, bufHS, n4);
    agg_k<<<gAg, TPB, 0, stream>>>(bufHS, ip_in, col_in, aggB, N);
    gemm_cat_k<true, true><<<gGm, TPB, 0, stream>>>(x, aggB, W1, b1, r_in, bufHS, bufH, N);

    // --- layer 2: 'I' — agg over out-edges of hs1 = fp16(h1 * r_in) ---
    agg_k<<<gAg, TPB, 0, stream>>>(bufHS, ip_out, col_out, aggB, N);
    gemm_cat_k<true, true><<<gGm, TPB, 0, stream>>>(bufH, aggB, W2, b2, r_und, bufHS, bufH, N);

    // --- layer 3: 'U' — agg both directions of hs2 = fp16(h2 * r_und) ---
    agg_dual_k<<<gAg, TPB, 0, stream>>>(bufHS, ip_in, col_in, ip_out, col_out, aggB, N);
    gemm_cat_k<false, false><<<gGm, TPB, 0, stream>>>(bufH, aggB, W3, b3, nullptr, nullptr,
                                                      (float*)d_out, N);
}